// Round 1
// baseline (516.421 us; speedup 1.0000x reference)
//
#include <hip/hip_runtime.h>

#define IN_DIM  128
#define HID_DIM 128
#define OUT_DIM 64
#define TM 32   // nodes per GEMM block tile

static inline size_t align256(size_t x) { return (x + 255) & ~size_t(255); }

// ---------------- graph prep ----------------

__global__ void hist_kernel(const int* __restrict__ dst, int* __restrict__ deg, int E) {
    int e = blockIdx.x * blockDim.x + threadIdx.x;
    if (e < E) atomicAdd(&deg[dst[e]], 1);
}

__global__ void scan_kernel(const int* __restrict__ deg, int* __restrict__ rowptr, int nNodes) {
    __shared__ int sh[1024];
    int tid = threadIdx.x;
    int C = (nNodes + 1023) / 1024;
    int start = tid * C;
    int local = 0;
    for (int i = 0; i < C; ++i) {
        int idx = start + i;
        if (idx < nNodes) local += deg[idx];
    }
    sh[tid] = local;
    __syncthreads();
    for (int off = 1; off < 1024; off <<= 1) {
        int v = (tid >= off) ? sh[tid - off] : 0;
        __syncthreads();
        sh[tid] += v;
        __syncthreads();
    }
    int run = sh[tid] - local;  // exclusive base
    for (int i = 0; i < C; ++i) {
        int idx = start + i;
        if (idx < nNodes) { rowptr[idx] = run; run += deg[idx]; }
    }
    if (tid == 1023) rowptr[nNodes] = sh[1023];
}

__global__ void fill_kernel(const int* __restrict__ src, const int* __restrict__ dst,
                            const int* __restrict__ rowptr, int* __restrict__ cursor,
                            int* __restrict__ col, int E) {
    int e = blockIdx.x * blockDim.x + threadIdx.x;
    if (e >= E) return;
    int d = dst[e];
    int p = rowptr[d] + atomicAdd(&cursor[d], 1);
    col[p] = src[e];
}

__global__ void dinv_kernel(const int* __restrict__ deg, float* __restrict__ dinv, int n) {
    int i = blockIdx.x * blockDim.x + threadIdx.x;
    if (i < n) {
        int d = deg[i]; if (d < 1) d = 1;
        dinv[i] = rsqrtf((float)d);
    }
}

// ---------------- aggregation: x1[n] = -dinv[n] * sum_{e: dst=n} x[src_e] * dinv[src_e] ----------------
// one wave (64 lanes) per node; lane covers 2 consecutive floats of the 128-float row

__global__ __launch_bounds__(256) void agg_kernel(
    const float* __restrict__ X, const int* __restrict__ rowptr,
    const int* __restrict__ col, const float* __restrict__ dinv,
    float* __restrict__ X1, int nNodes)
{
    int wid  = (blockIdx.x * blockDim.x + threadIdx.x) >> 6;
    int lane = threadIdx.x & 63;
    if (wid >= nNodes) return;
    int e0 = rowptr[wid], e1 = rowptr[wid + 1];
    float a0 = 0.f, a1 = 0.f;
    for (int e = e0; e < e1; ++e) {
        int s = col[e];
        float ds = dinv[s];
        float2 v = *reinterpret_cast<const float2*>(X + (size_t)s * 128 + lane * 2);
        a0 += v.x * ds;
        a1 += v.y * ds;
    }
    float sc = -dinv[wid];
    float2 r = make_float2(a0 * sc, a1 * sc);
    *reinterpret_cast<float2*>(X1 + (size_t)wid * 128 + lane * 2) = r;
}

// ---------------- GEMM: Y = [X | X1] @ W + b ;  K = 256 fixed, DOUT in {128, 64} ----------------

template <int DOUT>
__global__ __launch_bounds__(256) void gemm_cheb(
    const float* __restrict__ X, const float* __restrict__ X1,
    const float* __restrict__ W, const float* __restrict__ Bv,
    float* __restrict__ Y, int nNodes)
{
    constexpr int K = 256;
    constexpr int PAD = 36;                       // 144B rows: 16B-aligned, conflict-friendly
    constexpr int OG = DOUT / 4;                  // column groups of 4
    constexpr int TMT = (TM * DOUT) / (256 * 4);  // nodes per thread: 4 (DOUT=128) or 2 (DOUT=64)
    __shared__ float lds[K * PAD];

    int t = threadIdx.x;
    int base = blockIdx.x * TM;

    // load [x|x1] tile -> lds[k][n]
    {
        int nn = t & 31;
        int kc = t >> 5;  // 8 chunks of 32 k
        int node = base + nn;
        bool valid = node < nNodes;
        const float* xrow  = X  + (size_t)node * 128;
        const float* x1row = X1 + (size_t)node * 128;
        #pragma unroll
        for (int j = 0; j < 8; ++j) {
            int k = kc * 32 + j * 4;
            float4 v = make_float4(0.f, 0.f, 0.f, 0.f);
            if (valid) {
                const float* p = (k < 128) ? (xrow + k) : (x1row + (k - 128));
                v = *reinterpret_cast<const float4*>(p);
            }
            lds[(k + 0) * PAD + nn] = v.x;
            lds[(k + 1) * PAD + nn] = v.y;
            lds[(k + 2) * PAD + nn] = v.z;
            lds[(k + 3) * PAD + nn] = v.w;
        }
    }
    __syncthreads();

    int og = t % OG;
    int ng = t / OG;
    float acc[TMT][4];
    #pragma unroll
    for (int i = 0; i < TMT; ++i)
        #pragma unroll
        for (int j = 0; j < 4; ++j) acc[i][j] = 0.f;

    #pragma unroll 4
    for (int k = 0; k < K; ++k) {
        float4 w = *reinterpret_cast<const float4*>(W + (size_t)k * DOUT + og * 4);
        float xv[TMT];
        if constexpr (TMT == 4) {
            float4 v = *reinterpret_cast<const float4*>(&lds[k * PAD + ng * 4]);
            xv[0] = v.x; xv[1] = v.y; xv[2] = v.z; xv[3] = v.w;
        } else {
            float2 v = *reinterpret_cast<const float2*>(&lds[k * PAD + ng * 2]);
            xv[0] = v.x; xv[1] = v.y;
        }
        #pragma unroll
        for (int i = 0; i < TMT; ++i) {
            acc[i][0] += xv[i] * w.x;
            acc[i][1] += xv[i] * w.y;
            acc[i][2] += xv[i] * w.z;
            acc[i][3] += xv[i] * w.w;
        }
    }

    float4 b4 = *reinterpret_cast<const float4*>(Bv + og * 4);
    #pragma unroll
    for (int i = 0; i < TMT; ++i) {
        int node = base + ng * TMT + i;
        if (node < nNodes) {
            float4 r = make_float4(acc[i][0] + b4.x, acc[i][1] + b4.y,
                                   acc[i][2] + b4.z, acc[i][3] + b4.w);
            *reinterpret_cast<float4*>(Y + (size_t)node * DOUT + og * 4) = r;
        }
    }
}

// ---------------- host ----------------

extern "C" void kernel_launch(void* const* d_in, const int* in_sizes, int n_in,
                              void* d_out, int out_size, void* d_ws, size_t ws_size,
                              hipStream_t stream)
{
    const float* feats = (const float*)d_in[0];
    const int*   src   = (const int*)d_in[1];
    const int*   dst   = (const int*)d_in[2];
    const float* W1    = (const float*)d_in[3];
    const float* b1    = (const float*)d_in[4];
    const float* W2    = (const float*)d_in[5];
    const float* b2    = (const float*)d_in[6];
    float* out = (float*)d_out;

    const int N = in_sizes[0] / IN_DIM;
    const int E = in_sizes[1];

    char* ws = (char*)d_ws;
    size_t off = 0;
    int*   deg    = (int*)(ws + off);   off = align256(off + (size_t)N * 4);
    int*   cursor = (int*)(ws + off);   off = align256(off + (size_t)N * 4);
    int*   rowptr = (int*)(ws + off);   off = align256(off + (size_t)(N + 1) * 4);
    int*   col    = (int*)(ws + off);   off = align256(off + (size_t)E * 4);
    float* dinv   = (float*)(ws + off); off = align256(off + (size_t)N * 4);
    float* x1     = (float*)(ws + off); off = align256(off + (size_t)N * IN_DIM * 4);
    float* h1     = (float*)(ws + off); off = align256(off + (size_t)N * HID_DIM * 4);

    hipMemsetAsync(deg, 0, (size_t)N * 4, stream);
    hipMemsetAsync(cursor, 0, (size_t)N * 4, stream);

    hist_kernel<<<(E + 255) / 256, 256, 0, stream>>>(dst, deg, E);
    scan_kernel<<<1, 1024, 0, stream>>>(deg, rowptr, N);
    fill_kernel<<<(E + 255) / 256, 256, 0, stream>>>(src, dst, rowptr, cursor, col, E);
    dinv_kernel<<<(N + 255) / 256, 256, 0, stream>>>(deg, dinv, N);

    // layer 1
    agg_kernel<<<(N * 64 + 255) / 256, 256, 0, stream>>>(feats, rowptr, col, dinv, x1, N);
    gemm_cheb<HID_DIM><<<(N + TM - 1) / TM, 256, 0, stream>>>(feats, x1, W1, b1, h1, N);
    // layer 2
    agg_kernel<<<(N * 64 + 255) / 256, 256, 0, stream>>>(h1, rowptr, col, dinv, x1, N);
    gemm_cheb<OUT_DIM><<<(N + TM - 1) / TM, 256, 0, stream>>>(h1, x1, W2, b2, out, N);
}

// Round 2
// 324.434 us; speedup vs baseline: 1.5918x; 1.5918x over previous
//
#include <hip/hip_runtime.h>

#define IN_DIM  128

typedef __bf16 bf16x8 __attribute__((ext_vector_type(8)));
typedef float  f32x4  __attribute__((ext_vector_type(4)));

static inline size_t align256(size_t x) { return (x + 255) & ~size_t(255); }

// ---------- bf16 helpers (RNE) ----------
__device__ __forceinline__ ushort f2b1(float f) {
    union { float f; uint u; } c; c.f = f;
    uint u = c.u;
    uint r = (u + 0x7FFFu + ((u >> 16) & 1u)) >> 16;
    return (ushort)r;
}
__device__ __forceinline__ float b2f(uint v16) {
    union { uint u; float f; } c; c.u = v16 << 16; return c.f;
}

// ---------------- graph prep ----------------

__global__ void hist_kernel(const int* __restrict__ dst, int* __restrict__ deg, int E) {
    int e = blockIdx.x * blockDim.x + threadIdx.x;
    if (e < E) atomicAdd(&deg[dst[e]], 1);
}

// phase A: per-block (1024 elems) exclusive prescan + block sums
__global__ __launch_bounds__(256) void scan_blocks(const int* __restrict__ deg,
                                                   int* __restrict__ pre,
                                                   int* __restrict__ bsum, int n) {
    __shared__ int sh[256];
    int t = threadIdx.x;
    int base = blockIdx.x * 1024 + t * 4;
    int v0 = 0, v1 = 0, v2 = 0, v3 = 0;
    if (base + 3 < n) {
        int4 v = *reinterpret_cast<const int4*>(deg + base);
        v0 = v.x; v1 = v.y; v2 = v.z; v3 = v.w;
    } else {
        if (base     < n) v0 = deg[base];
        if (base + 1 < n) v1 = deg[base + 1];
        if (base + 2 < n) v2 = deg[base + 2];
        if (base + 3 < n) v3 = deg[base + 3];
    }
    int s = v0 + v1 + v2 + v3;
    sh[t] = s;
    __syncthreads();
    for (int off = 1; off < 256; off <<= 1) {
        int x = (t >= off) ? sh[t - off] : 0;
        __syncthreads();
        sh[t] += x;
        __syncthreads();
    }
    int excl = sh[t] - s;
    if (t == 255) bsum[blockIdx.x] = sh[255];
    if (base     < n) pre[base]     = excl;
    if (base + 1 < n) pre[base + 1] = excl + v0;
    if (base + 2 < n) pre[base + 2] = excl + v0 + v1;
    if (base + 3 < n) pre[base + 3] = excl + v0 + v1 + v2;
}

// phase B: exclusive scan of block sums (nb <= 64) with one wave
__global__ void scan_bsum(int* __restrict__ bsum, int nb) {
    int l = threadIdx.x;  // 64 lanes
    int orig = (l < nb) ? bsum[l] : 0;
    int v = orig;
    for (int off = 1; off < 64; off <<= 1) {
        int u = __shfl_up(v, off);
        if (l >= off) v += u;
    }
    if (l < nb) bsum[l] = v - orig;
}

// phase C: add block offsets
__global__ void scan_add(const int* __restrict__ pre, const int* __restrict__ bsum,
                         int* __restrict__ rowptr, int n, int E) {
    int i = blockIdx.x * blockDim.x + threadIdx.x;
    if (i < n) rowptr[i] = pre[i] + bsum[i >> 10];
    if (i == 0) rowptr[n] = E;
}

__global__ void fill_kernel(const int* __restrict__ src, const int* __restrict__ dst,
                            const int* __restrict__ rowptr, int* __restrict__ cursor,
                            int* __restrict__ col, int E) {
    int e = blockIdx.x * blockDim.x + threadIdx.x;
    if (e >= E) return;
    int d = dst[e];
    int p = rowptr[d] + atomicAdd(&cursor[d], 1);
    col[p] = src[e];
}

__global__ void dinv_kernel(const int* __restrict__ deg, float* __restrict__ dinv, int n) {
    int i = blockIdx.x * blockDim.x + threadIdx.x;
    if (i < n) {
        int d = deg[i]; if (d < 1) d = 1;
        dinv[i] = rsqrtf((float)d);
    }
}

// ---------------- conversions ----------------

__global__ void f2b_kernel(const float* __restrict__ in, ushort* __restrict__ out, int n4) {
    int i = blockIdx.x * blockDim.x + threadIdx.x;
    if (i >= n4) return;
    float4 v = *reinterpret_cast<const float4*>(in + (size_t)i * 4);
    ushort4 o;
    o.x = f2b1(v.x); o.y = f2b1(v.y); o.z = f2b1(v.z); o.w = f2b1(v.w);
    *reinterpret_cast<ushort4*>(out + (size_t)i * 4) = o;
}

// Wt[c][k] = bf16(W[k][c]) ; W is K x D
__global__ void wconv_kernel(const float* __restrict__ W, ushort* __restrict__ Wt, int K, int D) {
    int i = blockIdx.x * blockDim.x + threadIdx.x;
    if (i >= K * D) return;
    int k = i / D, c = i % D;
    Wt[(size_t)c * K + k] = f2b1(W[i]);
}

// ---------------- aggregation (bf16 in/out, fp32 accum) ----------------
// x1[n] = -dinv[n] * sum_{e: dst=n} x[src_e] * dinv[src_e]
// one wave per node; lane covers 2 bf16 (one dword) of the 128-elem row

__global__ __launch_bounds__(256) void agg_bf16(
    const ushort* __restrict__ X, const int* __restrict__ rowptr,
    const int* __restrict__ col, const float* __restrict__ dinv,
    ushort* __restrict__ X1, int nNodes)
{
    int wid  = (blockIdx.x * blockDim.x + threadIdx.x) >> 6;
    int lane = threadIdx.x & 63;
    if (wid >= nNodes) return;
    int e0 = rowptr[wid], e1 = rowptr[wid + 1];
    const uint* Xu = reinterpret_cast<const uint*>(X);
    float a0 = 0.f, a1 = 0.f;
    for (int e = e0; e < e1; ++e) {
        int s = col[e];
        float ds = dinv[s];
        uint v = Xu[(size_t)s * 64 + lane];
        a0 += b2f(v & 0xffffu) * ds;
        a1 += b2f(v >> 16) * ds;
    }
    float sc = -dinv[wid];
    uint o = (uint)f2b1(a0 * sc) | ((uint)f2b1(a1 * sc) << 16);
    reinterpret_cast<uint*>(X1)[(size_t)wid * 64 + lane] = o;
}

// ---------------- MFMA GEMM: Y = [XA | XB] @ W + b, K=256 ----------------
// XA/XB: row-major bf16, row stride 128. Wt: [DOUT][256] bf16 (pre-transposed).
// One wave per 16 nodes; wave computes all DOUT cols (DOUT/16 accum tiles).

template <int DOUT, bool OUTBF16>
__global__ __launch_bounds__(256) void gemm_mfma(
    const ushort* __restrict__ XA, const ushort* __restrict__ XB,
    const ushort* __restrict__ Wt, const float* __restrict__ bias,
    void* __restrict__ Yv, int nNodes)
{
    constexpr int NCT = DOUT / 16;
    int wave = threadIdx.x >> 6, lane = threadIdx.x & 63;
    int r16 = lane & 15, g = lane >> 4;
    int nodeBase = blockIdx.x * 64 + wave * 16;

    int arow = nodeBase + r16;
    if (arow > nNodes - 1) arow = nNodes - 1;   // clamp: garbage only pollutes its own (guarded) row
    const ushort* pa0 = XA + (size_t)arow * 128;
    const ushort* pa1 = XB + (size_t)arow * 128;

    f32x4 acc[NCT];
    #pragma unroll
    for (int i = 0; i < NCT; ++i) acc[i] = f32x4{0.f, 0.f, 0.f, 0.f};

    #pragma unroll
    for (int kb = 0; kb < 8; ++kb) {
        const ushort* pa = (kb < 4) ? pa0 : pa1;
        int kk = (kb & 3) * 32 + g * 8;
        bf16x8 a = *reinterpret_cast<const bf16x8*>(pa + kk);
        #pragma unroll
        for (int ct = 0; ct < NCT; ++ct) {
            int colc = ct * 16 + r16;
            bf16x8 b = *reinterpret_cast<const bf16x8*>(Wt + (size_t)colc * 256 + kb * 32 + g * 8);
            acc[ct] = __builtin_amdgcn_mfma_f32_16x16x32_bf16(a, b, acc[ct], 0, 0, 0);
        }
    }

    #pragma unroll
    for (int ct = 0; ct < NCT; ++ct) {
        float bv = bias[ct * 16 + r16];
        #pragma unroll
        for (int r = 0; r < 4; ++r) {
            int orow = nodeBase + g * 4 + r;
            if (orow < nNodes) {
                float v = acc[ct][r] + bv;
                if constexpr (OUTBF16)
                    ((ushort*)Yv)[(size_t)orow * DOUT + ct * 16 + r16] = f2b1(v);
                else
                    ((float*)Yv)[(size_t)orow * DOUT + ct * 16 + r16] = v;
            }
        }
    }
}

// ---------------- host ----------------

extern "C" void kernel_launch(void* const* d_in, const int* in_sizes, int n_in,
                              void* d_out, int out_size, void* d_ws, size_t ws_size,
                              hipStream_t stream)
{
    const float* feats = (const float*)d_in[0];
    const int*   src   = (const int*)d_in[1];
    const int*   dst   = (const int*)d_in[2];
    const float* W1    = (const float*)d_in[3];
    const float* b1    = (const float*)d_in[4];
    const float* W2    = (const float*)d_in[5];
    const float* b2    = (const float*)d_in[6];
    float* out = (float*)d_out;

    const int N = in_sizes[0] / IN_DIM;
    const int E = in_sizes[1];
    const int NB = (N + 1023) / 1024;

    char* ws = (char*)d_ws;
    size_t off = 0;
    int*    deg    = (int*)(ws + off);    off = align256(off + (size_t)N * 4);
    int*    cursor = (int*)(ws + off);    off = align256(off + (size_t)N * 4);
    int*    rowptr = (int*)(ws + off);    off = align256(off + (size_t)(N + 1) * 4);
    int*    pre    = (int*)(ws + off);    off = align256(off + (size_t)N * 4);
    int*    bsum   = (int*)(ws + off);    off = align256(off + (size_t)64 * 4);
    int*    col    = (int*)(ws + off);    off = align256(off + (size_t)E * 4);
    float*  dinv   = (float*)(ws + off);  off = align256(off + (size_t)N * 4);
    ushort* featb  = (ushort*)(ws + off); off = align256(off + (size_t)N * 128 * 2);
    ushort* x1b    = (ushort*)(ws + off); off = align256(off + (size_t)N * 128 * 2);
    ushort* h1b    = (ushort*)(ws + off); off = align256(off + (size_t)N * 128 * 2);
    ushort* W1t    = (ushort*)(ws + off); off = align256(off + (size_t)256 * 128 * 2);
    ushort* W2t    = (ushort*)(ws + off); off = align256(off + (size_t)256 * 64 * 2);

    hipMemsetAsync(deg, 0, (size_t)N * 4, stream);
    hipMemsetAsync(cursor, 0, (size_t)N * 4, stream);

    // graph prep
    hist_kernel<<<(E + 255) / 256, 256, 0, stream>>>(dst, deg, E);
    scan_blocks<<<NB, 256, 0, stream>>>(deg, pre, bsum, N);
    scan_bsum<<<1, 64, 0, stream>>>(bsum, NB);
    scan_add<<<(N + 255) / 256, 256, 0, stream>>>(pre, bsum, rowptr, N, E);
    fill_kernel<<<(E + 255) / 256, 256, 0, stream>>>(src, dst, rowptr, cursor, col, E);
    dinv_kernel<<<(N + 255) / 256, 256, 0, stream>>>(deg, dinv, N);

    // conversions
    f2b_kernel<<<((N * 128 / 4) + 255) / 256, 256, 0, stream>>>(feats, featb, N * 128 / 4);
    wconv_kernel<<<(256 * 128 + 255) / 256, 256, 0, stream>>>(W1, W1t, 256, 128);
    wconv_kernel<<<(256 * 64 + 255) / 256, 256, 0, stream>>>(W2, W2t, 256, 64);

    const int aggBlocks = (N * 64 + 255) / 256;
    const int gemmBlocks = (N + 63) / 64;

    // layer 1
    agg_bf16<<<aggBlocks, 256, 0, stream>>>(featb, rowptr, col, dinv, x1b, N);
    gemm_mfma<128, true><<<gemmBlocks, 256, 0, stream>>>(featb, x1b, W1t, b1, h1b, N);
    // layer 2
    agg_bf16<<<aggBlocks, 256, 0, stream>>>(h1b, rowptr, col, dinv, x1b, N);
    gemm_mfma<64, false><<<gemmBlocks, 256, 0, stream>>>(h1b, x1b, W2t, b2, out, N);
}

// Round 3
// 245.286 us; speedup vs baseline: 2.1054x; 1.3227x over previous
//
#include <hip/hip_runtime.h>

#define IN_DIM  128

typedef __bf16 bf16x8 __attribute__((ext_vector_type(8)));
typedef float  f32x4  __attribute__((ext_vector_type(4)));

static inline size_t align256(size_t x) { return (x + 255) & ~size_t(255); }

// ---------- bf16 helpers (RNE) ----------
__device__ __forceinline__ ushort f2b1(float f) {
    union { float f; uint u; } c; c.f = f;
    uint u = c.u;
    uint r = (u + 0x7FFFu + ((u >> 16) & 1u)) >> 16;
    return (ushort)r;
}
__device__ __forceinline__ float b2f(uint v16) {
    union { uint u; float f; } c; c.u = v16 << 16; return c.f;
}

// ---------------- graph prep ----------------

__global__ void hist_kernel(const int* __restrict__ dst, int* __restrict__ deg, int E) {
    int e = blockIdx.x * blockDim.x + threadIdx.x;
    if (e < E) atomicAdd(&deg[dst[e]], 1);
}

// phase A: per-block (1024 elems) exclusive prescan + block sums
__global__ __launch_bounds__(256) void scan_blocks(const int* __restrict__ deg,
                                                   int* __restrict__ pre,
                                                   int* __restrict__ bsum, int n) {
    __shared__ int sh[256];
    int t = threadIdx.x;
    int base = blockIdx.x * 1024 + t * 4;
    int v0 = 0, v1 = 0, v2 = 0, v3 = 0;
    if (base + 3 < n) {
        int4 v = *reinterpret_cast<const int4*>(deg + base);
        v0 = v.x; v1 = v.y; v2 = v.z; v3 = v.w;
    } else {
        if (base     < n) v0 = deg[base];
        if (base + 1 < n) v1 = deg[base + 1];
        if (base + 2 < n) v2 = deg[base + 2];
        if (base + 3 < n) v3 = deg[base + 3];
    }
    int s = v0 + v1 + v2 + v3;
    sh[t] = s;
    __syncthreads();
    for (int off = 1; off < 256; off <<= 1) {
        int x = (t >= off) ? sh[t - off] : 0;
        __syncthreads();
        sh[t] += x;
        __syncthreads();
    }
    int excl = sh[t] - s;
    if (t == 255) bsum[blockIdx.x] = sh[255];
    if (base     < n) pre[base]     = excl;
    if (base + 1 < n) pre[base + 1] = excl + v0;
    if (base + 2 < n) pre[base + 2] = excl + v0 + v1;
    if (base + 3 < n) pre[base + 3] = excl + v0 + v1 + v2;
}

// phase B: exclusive scan of block sums (nb <= 64) with one wave
__global__ void scan_bsum(int* __restrict__ bsum, int nb) {
    int l = threadIdx.x;  // 64 lanes
    int orig = (l < nb) ? bsum[l] : 0;
    int v = orig;
    for (int off = 1; off < 64; off <<= 1) {
        int u = __shfl_up(v, off);
        if (l >= off) v += u;
    }
    if (l < nb) bsum[l] = v - orig;
}

// phase C: add block offsets
__global__ void scan_add(const int* __restrict__ pre, const int* __restrict__ bsum,
                         int* __restrict__ rowptr, int n, int E) {
    int i = blockIdx.x * blockDim.x + threadIdx.x;
    if (i < n) rowptr[i] = pre[i] + bsum[i >> 10];
    if (i == 0) rowptr[n] = E;
}

__global__ void dinv_kernel(const int* __restrict__ deg, float* __restrict__ dinv, int n) {
    int i = blockIdx.x * blockDim.x + threadIdx.x;
    if (i < n) {
        int d = deg[i]; if (d < 1) d = 1;
        dinv[i] = rsqrtf((float)d);
    }
}

// fill CSR with packed records {src, dinv[src]}; consumes deg via atomic countdown
__global__ void fill_kernel(const int* __restrict__ src, const int* __restrict__ dst,
                            const int* __restrict__ rowptr, int* __restrict__ deg,
                            const float* __restrict__ dinv,
                            int2* __restrict__ rec, int E) {
    int e = blockIdx.x * blockDim.x + threadIdx.x;
    if (e >= E) return;
    int d = dst[e];
    int s = src[e];
    int r = atomicAdd(&deg[d], -1);          // returns old; slots rowptr[d] .. rowptr[d]+deg-1
    int p = rowptr[d] + r - 1;
    float w = dinv[s];
    rec[p] = make_int2(s, __float_as_int(w));
}

// ---------------- conversions ----------------

__global__ void f2b_kernel(const float* __restrict__ in, ushort* __restrict__ out, int n4) {
    int i = blockIdx.x * blockDim.x + threadIdx.x;
    if (i >= n4) return;
    float4 v = *reinterpret_cast<const float4*>(in + (size_t)i * 4);
    ushort4 o;
    o.x = f2b1(v.x); o.y = f2b1(v.y); o.z = f2b1(v.z); o.w = f2b1(v.w);
    *reinterpret_cast<ushort4*>(out + (size_t)i * 4) = o;
}

// Wt[c][k] = bf16(W[k][c]) ; W is K x D
__global__ void wconv_kernel(const float* __restrict__ W, ushort* __restrict__ Wt, int K, int D) {
    int i = blockIdx.x * blockDim.x + threadIdx.x;
    if (i >= K * D) return;
    int k = i / D, c = i % D;
    Wt[(size_t)c * K + k] = f2b1(W[i]);
}

// ---------------- aggregation (bf16 in/out, fp32 accum), 8-edge batches ----------------
// x1[n] = -dinv[n] * sum_{e: dst=n} x[src_e] * dinv[src_e]
// one wave per node; lane covers 2 bf16 (one dword) of the 128-elem row

__global__ __launch_bounds__(256) void agg_bf16(
    const ushort* __restrict__ X, const int* __restrict__ rowptr,
    const int2* __restrict__ rec, const float* __restrict__ dinv,
    ushort* __restrict__ X1, int nNodes)
{
    int wid  = (blockIdx.x * blockDim.x + threadIdx.x) >> 6;
    int lane = threadIdx.x & 63;
    if (wid >= nNodes) return;
    int e0 = rowptr[wid], e1 = rowptr[wid + 1];
    float sc = -dinv[wid];
    const uint* Xu = reinterpret_cast<const uint*>(X);

    float a0 = 0.f, a1 = 0.f;
    for (int e = e0; e < e1; e += 8) {
        int   s[8];
        float w[8];
        uint  v[8];
        #pragma unroll
        for (int j = 0; j < 8; ++j) {
            bool ok = (e + j) < e1;
            int2 r = rec[ok ? (e + j) : e0];
            s[j] = r.x;
            w[j] = ok ? __int_as_float(r.y) : 0.f;
        }
        #pragma unroll
        for (int j = 0; j < 8; ++j)
            v[j] = Xu[(size_t)s[j] * 64 + lane];
        #pragma unroll
        for (int j = 0; j < 8; ++j) {
            a0 += b2f(v[j] & 0xffffu) * w[j];
            a1 += b2f(v[j] >> 16) * w[j];
        }
    }
    uint o = (uint)f2b1(a0 * sc) | ((uint)f2b1(a1 * sc) << 16);
    reinterpret_cast<uint*>(X1)[(size_t)wid * 64 + lane] = o;
}

// ---------------- MFMA GEMM: Y = [XA | XB] @ W + b, K=256 ----------------
// XA/XB: row-major bf16, row stride 128. Wt: [DOUT][256] bf16 (pre-transposed).
// One wave per 16 nodes; wave computes all DOUT cols (DOUT/16 accum tiles).

template <int DOUT, bool OUTBF16>
__global__ __launch_bounds__(256) void gemm_mfma(
    const ushort* __restrict__ XA, const ushort* __restrict__ XB,
    const ushort* __restrict__ Wt, const float* __restrict__ bias,
    void* __restrict__ Yv, int nNodes)
{
    constexpr int NCT = DOUT / 16;
    int wave = threadIdx.x >> 6, lane = threadIdx.x & 63;
    int r16 = lane & 15, g = lane >> 4;
    int nodeBase = blockIdx.x * 64 + wave * 16;

    int arow = nodeBase + r16;
    if (arow > nNodes - 1) arow = nNodes - 1;   // clamp: garbage only pollutes its own (guarded) row
    const ushort* pa0 = XA + (size_t)arow * 128;
    const ushort* pa1 = XB + (size_t)arow * 128;

    f32x4 acc[NCT];
    #pragma unroll
    for (int i = 0; i < NCT; ++i) acc[i] = f32x4{0.f, 0.f, 0.f, 0.f};

    #pragma unroll
    for (int kb = 0; kb < 8; ++kb) {
        const ushort* pa = (kb < 4) ? pa0 : pa1;
        int kk = (kb & 3) * 32 + g * 8;
        bf16x8 a = *reinterpret_cast<const bf16x8*>(pa + kk);
        #pragma unroll
        for (int ct = 0; ct < NCT; ++ct) {
            int colc = ct * 16 + r16;
            bf16x8 b = *reinterpret_cast<const bf16x8*>(Wt + (size_t)colc * 256 + kb * 32 + g * 8);
            acc[ct] = __builtin_amdgcn_mfma_f32_16x16x32_bf16(a, b, acc[ct], 0, 0, 0);
        }
    }

    #pragma unroll
    for (int ct = 0; ct < NCT; ++ct) {
        float bv = bias[ct * 16 + r16];
        #pragma unroll
        for (int r = 0; r < 4; ++r) {
            int orow = nodeBase + g * 4 + r;
            if (orow < nNodes) {
                float v = acc[ct][r] + bv;
                if constexpr (OUTBF16)
                    ((ushort*)Yv)[(size_t)orow * DOUT + ct * 16 + r16] = f2b1(v);
                else
                    ((float*)Yv)[(size_t)orow * DOUT + ct * 16 + r16] = v;
            }
        }
    }
}

// ---------------- host ----------------

extern "C" void kernel_launch(void* const* d_in, const int* in_sizes, int n_in,
                              void* d_out, int out_size, void* d_ws, size_t ws_size,
                              hipStream_t stream)
{
    const float* feats = (const float*)d_in[0];
    const int*   src   = (const int*)d_in[1];
    const int*   dst   = (const int*)d_in[2];
    const float* W1    = (const float*)d_in[3];
    const float* b1    = (const float*)d_in[4];
    const float* W2    = (const float*)d_in[5];
    const float* b2    = (const float*)d_in[6];
    float* out = (float*)d_out;

    const int N = in_sizes[0] / IN_DIM;
    const int E = in_sizes[1];
    const int NB = (N + 1023) / 1024;

    char* ws = (char*)d_ws;
    size_t off = 0;
    int*    deg    = (int*)(ws + off);    off = align256(off + (size_t)N * 4);
    int*    rowptr = (int*)(ws + off);    off = align256(off + (size_t)(N + 1) * 4);
    int*    pre    = (int*)(ws + off);    off = align256(off + (size_t)N * 4);
    int*    bsum   = (int*)(ws + off);    off = align256(off + (size_t)64 * 4);
    int2*   rec    = (int2*)(ws + off);   off = align256(off + (size_t)E * 8);
    float*  dinv   = (float*)(ws + off);  off = align256(off + (size_t)N * 4);
    ushort* featb  = (ushort*)(ws + off); off = align256(off + (size_t)N * 128 * 2);
    ushort* x1b    = (ushort*)(ws + off); off = align256(off + (size_t)N * 128 * 2);
    ushort* h1b    = (ushort*)(ws + off); off = align256(off + (size_t)N * 128 * 2);
    ushort* W1t    = (ushort*)(ws + off); off = align256(off + (size_t)256 * 128 * 2);
    ushort* W2t    = (ushort*)(ws + off); off = align256(off + (size_t)256 * 64 * 2);

    hipMemsetAsync(deg, 0, (size_t)N * 4, stream);

    // graph prep
    hist_kernel<<<(E + 255) / 256, 256, 0, stream>>>(dst, deg, E);
    scan_blocks<<<NB, 256, 0, stream>>>(deg, pre, bsum, N);
    scan_bsum<<<1, 64, 0, stream>>>(bsum, NB);
    scan_add<<<(N + 255) / 256, 256, 0, stream>>>(pre, bsum, rowptr, N, E);
    dinv_kernel<<<(N + 255) / 256, 256, 0, stream>>>(deg, dinv, N);
    fill_kernel<<<(E + 255) / 256, 256, 0, stream>>>(src, dst, rowptr, deg, dinv, rec, E);

    // conversions (independent of graph prep)
    f2b_kernel<<<((N * 128 / 4) + 255) / 256, 256, 0, stream>>>(feats, featb, N * 128 / 4);
    wconv_kernel<<<(256 * 128 + 255) / 256, 256, 0, stream>>>(W1, W1t, 256, 128);
    wconv_kernel<<<(256 * 64 + 255) / 256, 256, 0, stream>>>(W2, W2t, 256, 64);

    const int aggBlocks = (N * 64 + 255) / 256;
    const int gemmBlocks = (N + 63) / 64;

    // layer 1
    agg_bf16<<<aggBlocks, 256, 0, stream>>>(featb, rowptr, rec, dinv, x1b, N);
    gemm_mfma<128, true><<<gemmBlocks, 256, 0, stream>>>(featb, x1b, W1t, b1, h1b, N);
    // layer 2
    agg_bf16<<<aggBlocks, 256, 0, stream>>>(h1b, rowptr, rec, dinv, x1b, N);
    gemm_mfma<64, false><<<gemmBlocks, 256, 0, stream>>>(h1b, x1b, W2t, b2, out, N);
}

// Round 4
// 212.135 us; speedup vs baseline: 2.4344x; 1.1563x over previous
//
#include <hip/hip_runtime.h>

#define IN_DIM  128

typedef __bf16 bf16x8 __attribute__((ext_vector_type(8)));
typedef float  f32x4  __attribute__((ext_vector_type(4)));

static inline size_t align256(size_t x) { return (x + 255) & ~size_t(255); }

// ---------- bf16 helpers (RNE) ----------
__device__ __forceinline__ ushort f2b1(float f) {
    union { float f; uint u; } c; c.f = f;
    uint u = c.u;
    uint r = (u + 0x7FFFu + ((u >> 16) & 1u)) >> 16;
    return (ushort)r;
}
__device__ __forceinline__ float b2f(uint v16) {
    union { uint u; float f; } c; c.u = v16 << 16; return c.f;
}

// ---------------- graph prep ----------------

__global__ void hist_kernel(const int* __restrict__ dst, int* __restrict__ deg, int E) {
    int e = blockIdx.x * blockDim.x + threadIdx.x;
    if (e < E) atomicAdd(&deg[dst[e]], 1);
}

// phase A: per-block (1024 elems) exclusive prescan + block sums
__global__ __launch_bounds__(256) void scan_blocks(const int* __restrict__ deg,
                                                   int* __restrict__ pre,
                                                   int* __restrict__ bsum, int n) {
    __shared__ int sh[256];
    int t = threadIdx.x;
    int base = blockIdx.x * 1024 + t * 4;
    int v0 = 0, v1 = 0, v2 = 0, v3 = 0;
    if (base + 3 < n) {
        int4 v = *reinterpret_cast<const int4*>(deg + base);
        v0 = v.x; v1 = v.y; v2 = v.z; v3 = v.w;
    } else {
        if (base     < n) v0 = deg[base];
        if (base + 1 < n) v1 = deg[base + 1];
        if (base + 2 < n) v2 = deg[base + 2];
        if (base + 3 < n) v3 = deg[base + 3];
    }
    int s = v0 + v1 + v2 + v3;
    sh[t] = s;
    __syncthreads();
    for (int off = 1; off < 256; off <<= 1) {
        int x = (t >= off) ? sh[t - off] : 0;
        __syncthreads();
        sh[t] += x;
        __syncthreads();
    }
    int excl = sh[t] - s;
    if (t == 255) bsum[blockIdx.x] = sh[255];
    if (base     < n) pre[base]     = excl;
    if (base + 1 < n) pre[base + 1] = excl + v0;
    if (base + 2 < n) pre[base + 2] = excl + v0 + v1;
    if (base + 3 < n) pre[base + 3] = excl + v0 + v1 + v2;
}

// phase B: exclusive scan of block sums (nb <= 64) with one wave
__global__ void scan_bsum(int* __restrict__ bsum, int nb) {
    int l = threadIdx.x;  // 64 lanes
    int orig = (l < nb) ? bsum[l] : 0;
    int v = orig;
    for (int off = 1; off < 64; off <<= 1) {
        int u = __shfl_up(v, off);
        if (l >= off) v += u;
    }
    if (l < nb) bsum[l] = v - orig;
}

// phase C: add block offsets + compute dinv (deg still intact here)
__global__ void scan_add(const int* __restrict__ pre, const int* __restrict__ bsum,
                         const int* __restrict__ deg,
                         int* __restrict__ rowptr, float* __restrict__ dinv,
                         int n, int E) {
    int i = blockIdx.x * blockDim.x + threadIdx.x;
    if (i < n) {
        rowptr[i] = pre[i] + bsum[i >> 10];
        int d = deg[i]; if (d < 1) d = 1;
        dinv[i] = rsqrtf((float)d);
    }
    if (i == 0) rowptr[n] = E;
}

// fill CSR with packed records {src, dinv[src]}; consumes deg via atomic countdown
__global__ void fill_kernel(const int* __restrict__ src, const int* __restrict__ dst,
                            const int* __restrict__ rowptr, int* __restrict__ deg,
                            const float* __restrict__ dinv,
                            int2* __restrict__ rec, int E) {
    int e = blockIdx.x * blockDim.x + threadIdx.x;
    if (e >= E) return;
    int d = dst[e];
    int s = src[e];
    int r = atomicAdd(&deg[d], -1);          // returns old; slots rowptr[d] .. rowptr[d]+deg-1
    int p = rowptr[d] + r - 1;
    float w = dinv[s];
    rec[p] = make_int2(s, __float_as_int(w));
}

// ---------------- fused conversions: feats->bf16, W1->W1t(bf16,T), W2->W2t(bf16,T) ----------------

__global__ __launch_bounds__(256) void conv_fused(
    const float* __restrict__ feats, ushort* __restrict__ featb, int nbF,  // nbF blocks of 1024 floats
    const float* __restrict__ W1, ushort* __restrict__ W1t,               // 256x128
    const float* __restrict__ W2, ushort* __restrict__ W2t)               // 256x64
{
    int b = blockIdx.x, t = threadIdx.x;
    if (b < nbF) {
        size_t i = ((size_t)b * 256 + t) * 4;
        float4 v = *reinterpret_cast<const float4*>(feats + i);
        ushort4 o;
        o.x = f2b1(v.x); o.y = f2b1(v.y); o.z = f2b1(v.z); o.w = f2b1(v.w);
        *reinterpret_cast<ushort4*>(featb + i) = o;
    } else if (b < nbF + 128) {
        int i = (b - nbF) * 256 + t;            // over 256*128
        int k = i >> 7, c = i & 127;
        W1t[(size_t)c * 256 + k] = f2b1(W1[i]);
    } else {
        int i = (b - nbF - 128) * 256 + t;      // over 256*64
        int k = i >> 6, c = i & 63;
        W2t[(size_t)c * 256 + k] = f2b1(W2[i]);
    }
}

// ---------------- aggregation (bf16 in/out, fp32 accum) ----------------
// x1[n] = -dinv[n] * sum_{e: dst=n} x[src_e] * dinv[src_e]
// one wave per node; lane covers 2 bf16 (one dword) of the 128-elem row.
// Lane l holds rec[e0+l]; per-edge src/w broadcast via readlane (SGPR base).

__device__ __forceinline__ void gather16(
    const uint* __restrict__ Xu, int lane, int slane, int wlane, int coff,
    float& a0, float& a1)
{
    uint v[16]; float w[16];
    #pragma unroll
    for (int j = 0; j < 16; ++j) {
        int s  = __builtin_amdgcn_readlane(slane, coff + j);
        int wb = __builtin_amdgcn_readlane(wlane, coff + j);
        w[j] = __int_as_float(wb);
        v[j] = Xu[(size_t)s * 64 + lane];
    }
    #pragma unroll
    for (int j = 0; j < 16; ++j) {
        a0 += b2f(v[j] & 0xffffu) * w[j];
        a1 += b2f(v[j] >> 16) * w[j];
    }
}

__global__ __launch_bounds__(256) void agg_bf16(
    const ushort* __restrict__ X, const int* __restrict__ rowptr,
    const int2* __restrict__ rec, const float* __restrict__ dinv,
    ushort* __restrict__ X1, int nNodes)
{
    int wid  = (blockIdx.x * blockDim.x + threadIdx.x) >> 6;
    int lane = threadIdx.x & 63;
    if (wid >= nNodes) return;
    int e0 = rowptr[wid], e1 = rowptr[wid + 1];
    float sc = -dinv[wid];
    const uint* Xu = reinterpret_cast<const uint*>(X);

    float a0 = 0.f, a1 = 0.f;
    for (int base = e0; base < e1; base += 64) {
        int idx = base + lane;
        int cl = (idx < e1) ? idx : (e1 - 1);   // e1 > base >= e0 >= 0 here
        int2 r = rec[cl];
        int slane = r.x;
        int wlane = (idx < e1) ? r.y : 0;       // bits of 0.0f for padding lanes
        int cnt = e1 - base; if (cnt > 64) cnt = 64;
        gather16(Xu, lane, slane, wlane, 0, a0, a1);
        if (cnt > 16) gather16(Xu, lane, slane, wlane, 16, a0, a1);
        if (cnt > 32) gather16(Xu, lane, slane, wlane, 32, a0, a1);
        if (cnt > 48) gather16(Xu, lane, slane, wlane, 48, a0, a1);
    }
    uint o = (uint)f2b1(a0 * sc) | ((uint)f2b1(a1 * sc) << 16);
    reinterpret_cast<uint*>(X1)[(size_t)wid * 64 + lane] = o;
}

// ---------------- MFMA GEMM: Y = [XA | XB] @ W + b, K=256 ----------------
// XA/XB: row-major bf16, row stride 128. Wt: [DOUT][256] bf16 (pre-transposed).
// One wave per 16 nodes; wave computes all DOUT cols (DOUT/16 accum tiles).

template <int DOUT, bool OUTBF16>
__global__ __launch_bounds__(256) void gemm_mfma(
    const ushort* __restrict__ XA, const ushort* __restrict__ XB,
    const ushort* __restrict__ Wt, const float* __restrict__ bias,
    void* __restrict__ Yv, int nNodes)
{
    constexpr int NCT = DOUT / 16;
    int wave = threadIdx.x >> 6, lane = threadIdx.x & 63;
    int r16 = lane & 15, g = lane >> 4;
    int nodeBase = blockIdx.x * 64 + wave * 16;

    int arow = nodeBase + r16;
    if (arow > nNodes - 1) arow = nNodes - 1;   // clamp: garbage only pollutes its own (guarded) row
    const ushort* pa0 = XA + (size_t)arow * 128;
    const ushort* pa1 = XB + (size_t)arow * 128;

    f32x4 acc[NCT];
    #pragma unroll
    for (int i = 0; i < NCT; ++i) acc[i] = f32x4{0.f, 0.f, 0.f, 0.f};

    #pragma unroll
    for (int kb = 0; kb < 8; ++kb) {
        const ushort* pa = (kb < 4) ? pa0 : pa1;
        int kk = (kb & 3) * 32 + g * 8;
        bf16x8 a = *reinterpret_cast<const bf16x8*>(pa + kk);
        #pragma unroll
        for (int ct = 0; ct < NCT; ++ct) {
            int colc = ct * 16 + r16;
            bf16x8 b = *reinterpret_cast<const bf16x8*>(Wt + (size_t)colc * 256 + kb * 32 + g * 8);
            acc[ct] = __builtin_amdgcn_mfma_f32_16x16x32_bf16(a, b, acc[ct], 0, 0, 0);
        }
    }

    #pragma unroll
    for (int ct = 0; ct < NCT; ++ct) {
        float bv = bias[ct * 16 + r16];
        #pragma unroll
        for (int r = 0; r < 4; ++r) {
            int orow = nodeBase + g * 4 + r;
            if (orow < nNodes) {
                float v = acc[ct][r] + bv;
                if constexpr (OUTBF16)
                    ((ushort*)Yv)[(size_t)orow * DOUT + ct * 16 + r16] = f2b1(v);
                else
                    ((float*)Yv)[(size_t)orow * DOUT + ct * 16 + r16] = v;
            }
        }
    }
}

// ---------------- host ----------------

extern "C" void kernel_launch(void* const* d_in, const int* in_sizes, int n_in,
                              void* d_out, int out_size, void* d_ws, size_t ws_size,
                              hipStream_t stream)
{
    const float* feats = (const float*)d_in[0];
    const int*   src   = (const int*)d_in[1];
    const int*   dst   = (const int*)d_in[2];
    const float* W1    = (const float*)d_in[3];
    const float* b1    = (const float*)d_in[4];
    const float* W2    = (const float*)d_in[5];
    const float* b2    = (const float*)d_in[6];
    float* out = (float*)d_out;

    const int N = in_sizes[0] / IN_DIM;
    const int E = in_sizes[1];
    const int NB = (N + 1023) / 1024;

    char* ws = (char*)d_ws;
    size_t off = 0;
    int*    deg    = (int*)(ws + off);    off = align256(off + (size_t)N * 4);
    int*    rowptr = (int*)(ws + off);    off = align256(off + (size_t)(N + 1) * 4);
    int*    pre    = (int*)(ws + off);    off = align256(off + (size_t)N * 4);
    int*    bsum   = (int*)(ws + off);    off = align256(off + (size_t)64 * 4);
    int2*   rec    = (int2*)(ws + off);   off = align256(off + (size_t)E * 8);
    float*  dinv   = (float*)(ws + off);  off = align256(off + (size_t)N * 4);
    ushort* featb  = (ushort*)(ws + off); off = align256(off + (size_t)N * 128 * 2);
    ushort* x1b    = (ushort*)(ws + off); off = align256(off + (size_t)N * 128 * 2);
    ushort* h1b    = (ushort*)(ws + off); off = align256(off + (size_t)N * 128 * 2);
    ushort* W1t    = (ushort*)(ws + off); off = align256(off + (size_t)256 * 128 * 2);
    ushort* W2t    = (ushort*)(ws + off); off = align256(off + (size_t)256 * 64 * 2);

    hipMemsetAsync(deg, 0, (size_t)N * 4, stream);

    // graph prep
    hist_kernel<<<(E + 255) / 256, 256, 0, stream>>>(dst, deg, E);
    scan_blocks<<<NB, 256, 0, stream>>>(deg, pre, bsum, N);
    scan_bsum<<<1, 64, 0, stream>>>(bsum, NB);
    scan_add<<<(N + 255) / 256, 256, 0, stream>>>(pre, bsum, deg, rowptr, dinv, N, E);
    fill_kernel<<<(E + 255) / 256, 256, 0, stream>>>(src, dst, rowptr, deg, dinv, rec, E);

    // fused conversions (independent of graph prep)
    const int nbF = (N * 128) / 1024;   // feats blocks (1024 floats each)
    conv_fused<<<nbF + 128 + 64, 256, 0, stream>>>(feats, featb, nbF, W1, W1t, W2, W2t);

    const int aggBlocks = (N * 64 + 255) / 256;
    const int gemmBlocks = (N + 63) / 64;

    // layer 1
    agg_bf16<<<aggBlocks, 256, 0, stream>>>(featb, rowptr, rec, dinv, x1b, N);
    gemm_mfma<128, true><<<gemmBlocks, 256, 0, stream>>>(featb, x1b, W1t, b1, h1b, N);
    // layer 2
    agg_bf16<<<aggBlocks, 256, 0, stream>>>(h1b, rowptr, rec, dinv, x1b, N);
    gemm_mfma<64, false><<<gemmBlocks, 256, 0, stream>>>(h1b, x1b, W2t, b2, out, N);
}

// Round 5
// 208.932 us; speedup vs baseline: 2.4717x; 1.0153x over previous
//
#include <hip/hip_runtime.h>

#define IN_DIM  128

typedef __bf16 bf16x8 __attribute__((ext_vector_type(8)));
typedef float  f32x4  __attribute__((ext_vector_type(4)));

static inline size_t align256(size_t x) { return (x + 255) & ~size_t(255); }

// ---------- bf16 helpers (RNE) ----------
__device__ __forceinline__ ushort f2b1(float f) {
    union { float f; uint u; } c; c.f = f;
    uint u = c.u;
    uint r = (u + 0x7FFFu + ((u >> 16) & 1u)) >> 16;
    return (ushort)r;
}
__device__ __forceinline__ float b2f(uint v16) {
    union { uint u; float f; } c; c.u = v16 << 16; return c.f;
}

// ---------------- graph prep ----------------

__global__ void hist_kernel(const int* __restrict__ dst, int* __restrict__ deg, int E) {
    int e = blockIdx.x * blockDim.x + threadIdx.x;
    if (e < E) atomicAdd(&deg[dst[e]], 1);
}

// phase A: per-block (1024 elems) exclusive prescan + block sums
__global__ __launch_bounds__(256) void scan_blocks(const int* __restrict__ deg,
                                                   int* __restrict__ pre,
                                                   int* __restrict__ bsum, int n) {
    __shared__ int sh[256];
    int t = threadIdx.x;
    int base = blockIdx.x * 1024 + t * 4;
    int v0 = 0, v1 = 0, v2 = 0, v3 = 0;
    if (base + 3 < n) {
        int4 v = *reinterpret_cast<const int4*>(deg + base);
        v0 = v.x; v1 = v.y; v2 = v.z; v3 = v.w;
    } else {
        if (base     < n) v0 = deg[base];
        if (base + 1 < n) v1 = deg[base + 1];
        if (base + 2 < n) v2 = deg[base + 2];
        if (base + 3 < n) v3 = deg[base + 3];
    }
    int s = v0 + v1 + v2 + v3;
    sh[t] = s;
    __syncthreads();
    for (int off = 1; off < 256; off <<= 1) {
        int x = (t >= off) ? sh[t - off] : 0;
        __syncthreads();
        sh[t] += x;
        __syncthreads();
    }
    int excl = sh[t] - s;
    if (t == 255) bsum[blockIdx.x] = sh[255];
    if (base     < n) pre[base]     = excl;
    if (base + 1 < n) pre[base + 1] = excl + v0;
    if (base + 2 < n) pre[base + 2] = excl + v0 + v1;
    if (base + 3 < n) pre[base + 3] = excl + v0 + v1 + v2;
}

// phase B: exclusive scan of block sums (nb <= 64) with one wave
__global__ void scan_bsum(int* __restrict__ bsum, int nb) {
    int l = threadIdx.x;  // 64 lanes
    int orig = (l < nb) ? bsum[l] : 0;
    int v = orig;
    for (int off = 1; off < 64; off <<= 1) {
        int u = __shfl_up(v, off);
        if (l >= off) v += u;
    }
    if (l < nb) bsum[l] = v - orig;
}

// phase C: add block offsets + compute dinv (deg still intact here)
__global__ void scan_add(const int* __restrict__ pre, const int* __restrict__ bsum,
                         const int* __restrict__ deg,
                         int* __restrict__ rowptr, float* __restrict__ dinv,
                         int n, int E) {
    int i = blockIdx.x * blockDim.x + threadIdx.x;
    if (i < n) {
        rowptr[i] = pre[i] + bsum[i >> 10];
        int d = deg[i]; if (d < 1) d = 1;
        dinv[i] = rsqrtf((float)d);
    }
    if (i == 0) rowptr[n] = E;
}

// fill CSR col (src only, 2B when N<=65535); consumes deg via atomic countdown
template <typename CT>
__global__ void fill_kernel(const int* __restrict__ src, const int* __restrict__ dst,
                            const int* __restrict__ rowptr, int* __restrict__ deg,
                            CT* __restrict__ col, int E) {
    int e = blockIdx.x * blockDim.x + threadIdx.x;
    if (e >= E) return;
    int d = dst[e];
    int r = atomicAdd(&deg[d], -1);          // returns old; slots rowptr[d] .. rowptr[d]+deg-1
    col[rowptr[d] + r - 1] = (CT)src[e];
}

// ---------------- fused conversions ----------------
// feats->bf16; W1->W1t [128 cols][256 k]; W2->W2ct combined [128 cols][128 k]
// W2ct col c<64: y_top col c -> W2[k][c]; col c>=64: z2 col (c-64) -> W2[128+k][c-64]

__global__ __launch_bounds__(256) void conv_fused(
    const float* __restrict__ feats, ushort* __restrict__ featb, int nbF,
    const float* __restrict__ W1, ushort* __restrict__ W1t,
    const float* __restrict__ W2, ushort* __restrict__ W2ct)
{
    int b = blockIdx.x, t = threadIdx.x;
    if (b < nbF) {
        size_t i = ((size_t)b * 256 + t) * 4;
        float4 v = *reinterpret_cast<const float4*>(feats + i);
        ushort4 o;
        o.x = f2b1(v.x); o.y = f2b1(v.y); o.z = f2b1(v.z); o.w = f2b1(v.w);
        *reinterpret_cast<ushort4*>(featb + i) = o;
    } else if (b < nbF + 128) {
        int i = (b - nbF) * 256 + t;            // over 256*128
        int k = i >> 7, c = i & 127;
        W1t[(size_t)c * 256 + k] = f2b1(W1[i]);
    } else {
        int i = (b - nbF - 128) * 256 + t;      // over 128*128
        int c = i >> 7, k = i & 127;
        float v = (c < 64) ? W2[(size_t)k * 64 + c]
                           : W2[(size_t)(128 + k) * 64 + (c - 64)];
        W2ct[(size_t)c * 128 + k] = f2b1(v);
    }
}

// ---------------- aggregation layer 1 (bf16 rows of 128) ----------------
// x1[n] = -dinv[n] * sum_e x[src_e] * dinv[src_e]; one wave/node, lane = 1 dword (2 bf16)

__device__ __forceinline__ void gather16(
    const uint* __restrict__ Xu, int lane, int slane, int wlane, int coff,
    float& a0, float& a1)
{
    uint v[16]; float w[16];
    #pragma unroll
    for (int j = 0; j < 16; ++j) {
        int s  = __builtin_amdgcn_readlane(slane, coff + j);
        int wb = __builtin_amdgcn_readlane(wlane, coff + j);
        w[j] = __int_as_float(wb);
        v[j] = Xu[(size_t)s * 64 + lane];
    }
    #pragma unroll
    for (int j = 0; j < 16; ++j) {
        a0 += b2f(v[j] & 0xffffu) * w[j];
        a1 += b2f(v[j] >> 16) * w[j];
    }
}

template <typename CT>
__global__ __launch_bounds__(256) void agg_bf16(
    const ushort* __restrict__ X, const int* __restrict__ rowptr,
    const CT* __restrict__ col, const float* __restrict__ dinv,
    ushort* __restrict__ X1, int nNodes)
{
    int wid  = (blockIdx.x * blockDim.x + threadIdx.x) >> 6;
    int lane = threadIdx.x & 63;
    if (wid >= nNodes) return;
    int e0 = rowptr[wid], e1 = rowptr[wid + 1];
    float sc = -dinv[wid];
    const uint* Xu = reinterpret_cast<const uint*>(X);

    float a0 = 0.f, a1 = 0.f;
    for (int base = e0; base < e1; base += 64) {
        int idx = base + lane;
        int cl = (idx < e1) ? idx : (e1 - 1);
        int s = (int)col[cl];
        float w = (idx < e1) ? dinv[s] : 0.f;
        int wlane = __float_as_int(w);
        int cnt = e1 - base; if (cnt > 64) cnt = 64;
        gather16(Xu, lane, s, wlane, 0, a0, a1);
        if (cnt > 16) gather16(Xu, lane, s, wlane, 16, a0, a1);
        if (cnt > 32) gather16(Xu, lane, s, wlane, 32, a0, a1);
        if (cnt > 48) gather16(Xu, lane, s, wlane, 48, a0, a1);
    }
    uint o = (uint)f2b1(a0 * sc) | ((uint)f2b1(a1 * sc) << 16);
    reinterpret_cast<uint*>(X1)[(size_t)wid * 64 + lane] = o;
}

// ---------------- aggregation layer 2 (bf16 rows of 64, FMA into fp32 out) ----------------
// out[n][l] += -dinv[n] * sum_e Z2[src_e][l] * dinv[src_e]; one wave/node, lane = 1 col

__device__ __forceinline__ void gather16z(
    const ushort* __restrict__ Z, int lane, int slane, int wlane, int coff, float& a0)
{
    uint v[16]; float w[16];
    #pragma unroll
    for (int j = 0; j < 16; ++j) {
        int s  = __builtin_amdgcn_readlane(slane, coff + j);
        int wb = __builtin_amdgcn_readlane(wlane, coff + j);
        w[j] = __int_as_float(wb);
        v[j] = Z[(size_t)s * 64 + lane];
    }
    #pragma unroll
    for (int j = 0; j < 16; ++j)
        a0 += b2f(v[j]) * w[j];
}

template <typename CT>
__global__ __launch_bounds__(256) void agg_add64(
    const ushort* __restrict__ Z2, const int* __restrict__ rowptr,
    const CT* __restrict__ col, const float* __restrict__ dinv,
    float* __restrict__ Y, int nNodes)
{
    int wid  = (blockIdx.x * blockDim.x + threadIdx.x) >> 6;
    int lane = threadIdx.x & 63;
    if (wid >= nNodes) return;
    int e0 = rowptr[wid], e1 = rowptr[wid + 1];
    float sc = -dinv[wid];

    float a0 = 0.f;
    for (int base = e0; base < e1; base += 64) {
        int idx = base + lane;
        int cl = (idx < e1) ? idx : (e1 - 1);
        int s = (int)col[cl];
        float w = (idx < e1) ? dinv[s] : 0.f;
        int wlane = __float_as_int(w);
        int cnt = e1 - base; if (cnt > 64) cnt = 64;
        gather16z(Z2, lane, s, wlane, 0, a0);
        if (cnt > 16) gather16z(Z2, lane, s, wlane, 16, a0);
        if (cnt > 32) gather16z(Z2, lane, s, wlane, 32, a0);
        if (cnt > 48) gather16z(Z2, lane, s, wlane, 48, a0);
    }
    Y[(size_t)wid * 64 + lane] += a0 * sc;
}

// ---------------- MFMA GEMM layer 1: h1 = [XA | XB] @ W1 + b1, K=256, 128 cols, bf16 out ----------------

__global__ __launch_bounds__(256) void gemm_mfma1(
    const ushort* __restrict__ XA, const ushort* __restrict__ XB,
    const ushort* __restrict__ Wt, const float* __restrict__ bias,
    ushort* __restrict__ Y, int nNodes)
{
    constexpr int NCT = 8;  // 128 cols
    int wave = threadIdx.x >> 6, lane = threadIdx.x & 63;
    int r16 = lane & 15, g = lane >> 4;
    int nodeBase = blockIdx.x * 64 + wave * 16;

    int arow = nodeBase + r16;
    if (arow > nNodes - 1) arow = nNodes - 1;
    const ushort* pa0 = XA + (size_t)arow * 128;
    const ushort* pa1 = XB + (size_t)arow * 128;

    f32x4 acc[NCT];
    #pragma unroll
    for (int i = 0; i < NCT; ++i) acc[i] = f32x4{0.f, 0.f, 0.f, 0.f};

    #pragma unroll
    for (int kb = 0; kb < 8; ++kb) {
        const ushort* pa = (kb < 4) ? pa0 : pa1;
        int kk = (kb & 3) * 32 + g * 8;
        bf16x8 a = *reinterpret_cast<const bf16x8*>(pa + kk);
        #pragma unroll
        for (int ct = 0; ct < NCT; ++ct) {
            int colc = ct * 16 + r16;
            bf16x8 b = *reinterpret_cast<const bf16x8*>(Wt + (size_t)colc * 256 + kb * 32 + g * 8);
            acc[ct] = __builtin_amdgcn_mfma_f32_16x16x32_bf16(a, b, acc[ct], 0, 0, 0);
        }
    }

    #pragma unroll
    for (int ct = 0; ct < NCT; ++ct) {
        float bv = bias[ct * 16 + r16];
        #pragma unroll
        for (int r = 0; r < 4; ++r) {
            int orow = nodeBase + g * 4 + r;
            if (orow < nNodes)
                Y[(size_t)orow * 128 + ct * 16 + r16] = f2b1(acc[ct][r] + bv);
        }
    }
}

// ---------------- MFMA GEMM layer 2 fused: [y_top | Z2] = h1 @ W2c, K=128 ----------------
// cols 0-63 -> out fp32 (+bias); cols 64-127 -> Z2 bf16

__global__ __launch_bounds__(256) void gemm_mfma2(
    const ushort* __restrict__ H1, const ushort* __restrict__ W2ct,
    const float* __restrict__ bias, float* __restrict__ Yout,
    ushort* __restrict__ Z2, int nNodes)
{
    constexpr int NCT = 8;  // 128 combined cols
    int wave = threadIdx.x >> 6, lane = threadIdx.x & 63;
    int r16 = lane & 15, g = lane >> 4;
    int nodeBase = blockIdx.x * 64 + wave * 16;

    int arow = nodeBase + r16;
    if (arow > nNodes - 1) arow = nNodes - 1;
    const ushort* pa0 = H1 + (size_t)arow * 128;

    f32x4 acc[NCT];
    #pragma unroll
    for (int i = 0; i < NCT; ++i) acc[i] = f32x4{0.f, 0.f, 0.f, 0.f};

    #pragma unroll
    for (int kb = 0; kb < 4; ++kb) {
        int kk = kb * 32 + g * 8;
        bf16x8 a = *reinterpret_cast<const bf16x8*>(pa0 + kk);
        #pragma unroll
        for (int ct = 0; ct < NCT; ++ct) {
            int colc = ct * 16 + r16;
            bf16x8 b = *reinterpret_cast<const bf16x8*>(W2ct + (size_t)colc * 128 + kk);
            acc[ct] = __builtin_amdgcn_mfma_f32_16x16x32_bf16(a, b, acc[ct], 0, 0, 0);
        }
    }

    #pragma unroll
    for (int ct = 0; ct < NCT; ++ct) {
        float bv = (ct < 4) ? bias[ct * 16 + r16] : 0.f;
        #pragma unroll
        for (int r = 0; r < 4; ++r) {
            int orow = nodeBase + g * 4 + r;
            if (orow < nNodes) {
                if (ct < 4)
                    Yout[(size_t)orow * 64 + ct * 16 + r16] = acc[ct][r] + bv;
                else
                    Z2[(size_t)orow * 64 + (ct - 4) * 16 + r16] = f2b1(acc[ct][r]);
            }
        }
    }
}

// ---------------- host ----------------

extern "C" void kernel_launch(void* const* d_in, const int* in_sizes, int n_in,
                              void* d_out, int out_size, void* d_ws, size_t ws_size,
                              hipStream_t stream)
{
    const float* feats = (const float*)d_in[0];
    const int*   src   = (const int*)d_in[1];
    const int*   dst   = (const int*)d_in[2];
    const float* W1    = (const float*)d_in[3];
    const float* b1    = (const float*)d_in[4];
    const float* W2    = (const float*)d_in[5];
    const float* b2    = (const float*)d_in[6];
    float* out = (float*)d_out;

    const int N = in_sizes[0] / IN_DIM;
    const int E = in_sizes[1];
    const int NB = (N + 1023) / 1024;

    char* ws = (char*)d_ws;
    size_t off = 0;
    int*    deg    = (int*)(ws + off);    off = align256(off + (size_t)N * 4);
    int*    rowptr = (int*)(ws + off);    off = align256(off + (size_t)(N + 1) * 4);
    int*    pre    = (int*)(ws + off);    off = align256(off + (size_t)N * 4);
    int*    bsum   = (int*)(ws + off);    off = align256(off + (size_t)64 * 4);
    void*   colv   = (void*)(ws + off);   off = align256(off + (size_t)E * 4);  // 2B or 4B per edge
    float*  dinv   = (float*)(ws + off);  off = align256(off + (size_t)N * 4);
    ushort* featb  = (ushort*)(ws + off); off = align256(off + (size_t)N * 128 * 2);
    ushort* x1b    = (ushort*)(ws + off); off = align256(off + (size_t)N * 128 * 2);
    ushort* h1b    = (ushort*)(ws + off); off = align256(off + (size_t)N * 128 * 2);
    ushort* z2b    = (ushort*)(ws + off); off = align256(off + (size_t)N * 64 * 2);
    ushort* W1t    = (ushort*)(ws + off); off = align256(off + (size_t)256 * 128 * 2);
    ushort* W2ct   = (ushort*)(ws + off); off = align256(off + (size_t)128 * 128 * 2);

    hipMemsetAsync(deg, 0, (size_t)N * 4, stream);

    // graph prep
    hist_kernel<<<(E + 255) / 256, 256, 0, stream>>>(dst, deg, E);
    scan_blocks<<<NB, 256, 0, stream>>>(deg, pre, bsum, N);
    scan_bsum<<<1, 64, 0, stream>>>(bsum, NB);
    scan_add<<<(N + 255) / 256, 256, 0, stream>>>(pre, bsum, deg, rowptr, dinv, N, E);

    const bool small = (N <= 65535);
    if (small)
        fill_kernel<ushort><<<(E + 255) / 256, 256, 0, stream>>>(src, dst, rowptr, deg, (ushort*)colv, E);
    else
        fill_kernel<uint><<<(E + 255) / 256, 256, 0, stream>>>(src, dst, rowptr, deg, (uint*)colv, E);

    // fused conversions (independent of graph prep)
    const int nbF = (N * 128) / 1024;
    conv_fused<<<nbF + 128 + 64, 256, 0, stream>>>(feats, featb, nbF, W1, W1t, W2, W2ct);

    const int aggBlocks = (N * 64 + 255) / 256;
    const int gemmBlocks = (N + 63) / 64;

    // layer 1: x1 = -A_hat x ; h1 = [x | x1] @ W1 + b1
    if (small)
        agg_bf16<ushort><<<aggBlocks, 256, 0, stream>>>(featb, rowptr, (const ushort*)colv, dinv, x1b, N);
    else
        agg_bf16<uint><<<aggBlocks, 256, 0, stream>>>(featb, rowptr, (const uint*)colv, dinv, x1b, N);
    gemm_mfma1<<<gemmBlocks, 256, 0, stream>>>(featb, x1b, W1t, b1, h1b, N);

    // layer 2 (reordered): [y_top | Z2] = h1 @ W2c ; out = y_top + (-A_hat Z2)
    gemm_mfma2<<<gemmBlocks, 256, 0, stream>>>(h1b, W2ct, b2, out, z2b, N);
    if (small)
        agg_add64<ushort><<<aggBlocks, 256, 0, stream>>>(z2b, rowptr, (const ushort*)colv, dinv, out, N);
    else
        agg_add64<uint><<<aggBlocks, 256, 0, stream>>>(z2b, rowptr, (const uint*)colv, dinv, out, N);
}

// Round 6
// 182.345 us; speedup vs baseline: 2.8321x; 1.1458x over previous
//
#include <hip/hip_runtime.h>

#define IN_DIM  128

typedef __bf16 bf16x8 __attribute__((ext_vector_type(8)));
typedef float  f32x4  __attribute__((ext_vector_type(4)));

static inline size_t align256(size_t x) { return (x + 255) & ~size_t(255); }

// ---------- bf16 helpers (RNE) ----------
__device__ __forceinline__ ushort f2b1(float f) {
    union { float f; uint u; } c; c.f = f;
    uint u = c.u;
    uint r = (u + 0x7FFFu + ((u >> 16) & 1u)) >> 16;
    return (ushort)r;
}
__device__ __forceinline__ float b2f(uint v16) {
    union { uint u; float f; } c; c.u = v16 << 16; return c.f;
}

// ---------------- graph prep ----------------

__global__ void zero_kernel(int4* __restrict__ p, int n16) {
    int i = blockIdx.x * blockDim.x + threadIdx.x;
    if (i < n16) p[i] = make_int4(0, 0, 0, 0);
}

// histogram + per-edge rank (order within its dst bucket)
__global__ void hist_kernel(const int* __restrict__ dst, int* __restrict__ deg,
                            int* __restrict__ rank, int E) {
    int e = blockIdx.x * blockDim.x + threadIdx.x;
    if (e < E) rank[e] = atomicAdd(&deg[dst[e]], 1);
}

// phase A: per-block (1024 elems) exclusive prescan + block sums
__global__ __launch_bounds__(256) void scan_blocks(const int* __restrict__ deg,
                                                   int* __restrict__ pre,
                                                   int* __restrict__ bsum, int n) {
    __shared__ int sh[256];
    int t = threadIdx.x;
    int base = blockIdx.x * 1024 + t * 4;
    int v0 = 0, v1 = 0, v2 = 0, v3 = 0;
    if (base + 3 < n) {
        int4 v = *reinterpret_cast<const int4*>(deg + base);
        v0 = v.x; v1 = v.y; v2 = v.z; v3 = v.w;
    } else {
        if (base     < n) v0 = deg[base];
        if (base + 1 < n) v1 = deg[base + 1];
        if (base + 2 < n) v2 = deg[base + 2];
        if (base + 3 < n) v3 = deg[base + 3];
    }
    int s = v0 + v1 + v2 + v3;
    sh[t] = s;
    __syncthreads();
    for (int off = 1; off < 256; off <<= 1) {
        int x = (t >= off) ? sh[t - off] : 0;
        __syncthreads();
        sh[t] += x;
        __syncthreads();
    }
    int excl = sh[t] - s;
    if (t == 255) bsum[blockIdx.x] = sh[255];
    if (base     < n) pre[base]     = excl;
    if (base + 1 < n) pre[base + 1] = excl + v0;
    if (base + 2 < n) pre[base + 2] = excl + v0 + v1;
    if (base + 3 < n) pre[base + 3] = excl + v0 + v1 + v2;
}

// phase B: exclusive scan of block sums (nb <= 64) with one wave
__global__ void scan_bsum(int* __restrict__ bsum, int nb) {
    int l = threadIdx.x;  // 64 lanes
    int orig = (l < nb) ? bsum[l] : 0;
    int v = orig;
    for (int off = 1; off < 64; off <<= 1) {
        int u = __shfl_up(v, off);
        if (l >= off) v += u;
    }
    if (l < nb) bsum[l] = v - orig;
}

// phase C: add block offsets + compute dinv
__global__ void scan_add(const int* __restrict__ pre, const int* __restrict__ bsum,
                         const int* __restrict__ deg,
                         int* __restrict__ rowptr, float* __restrict__ dinv,
                         int n, int E) {
    int i = blockIdx.x * blockDim.x + threadIdx.x;
    if (i < n) {
        rowptr[i] = pre[i] + bsum[i >> 10];
        int d = deg[i]; if (d < 1) d = 1;
        dinv[i] = rsqrtf((float)d);
    }
    if (i == 0) rowptr[n] = E;
}

// fill CSR col (no atomics): col[rowptr[dst]+rank] = src ; 4 edges/thread
template <typename CT>
__global__ __launch_bounds__(256) void fill_kernel(
    const int* __restrict__ src, const int* __restrict__ dst,
    const int* __restrict__ rowptr, const int* __restrict__ rank,
    CT* __restrict__ col, int E)
{
    int e0 = (blockIdx.x * blockDim.x + threadIdx.x) * 4;
    if (e0 + 3 < E) {
        int4 d4 = *reinterpret_cast<const int4*>(dst + e0);
        int4 r4 = *reinterpret_cast<const int4*>(rank + e0);
        int4 s4 = *reinterpret_cast<const int4*>(src + e0);
        int p0 = rowptr[d4.x] + r4.x;
        int p1 = rowptr[d4.y] + r4.y;
        int p2 = rowptr[d4.z] + r4.z;
        int p3 = rowptr[d4.w] + r4.w;
        col[p0] = (CT)s4.x;
        col[p1] = (CT)s4.y;
        col[p2] = (CT)s4.z;
        col[p3] = (CT)s4.w;
    } else {
        for (int e = e0; e < E; ++e)
            col[rowptr[dst[e]] + rank[e]] = (CT)src[e];
    }
}

// ---------------- fused conversions ----------------
// feats->bf16; W1->W1t [128 cols][256 k]; W2->W2ct combined [128 cols][128 k]
// W2ct col c<64: y_top col c -> W2[k][c]; col c>=64: z2 col (c-64) -> W2[128+k][c-64]

__global__ __launch_bounds__(256) void conv_fused(
    const float* __restrict__ feats, ushort* __restrict__ featb, int nbF,
    const float* __restrict__ W1, ushort* __restrict__ W1t,
    const float* __restrict__ W2, ushort* __restrict__ W2ct)
{
    int b = blockIdx.x, t = threadIdx.x;
    if (b < nbF) {
        size_t i = ((size_t)b * 256 + t) * 4;
        float4 v = *reinterpret_cast<const float4*>(feats + i);
        ushort4 o;
        o.x = f2b1(v.x); o.y = f2b1(v.y); o.z = f2b1(v.z); o.w = f2b1(v.w);
        *reinterpret_cast<ushort4*>(featb + i) = o;
    } else if (b < nbF + 128) {
        int i = (b - nbF) * 256 + t;            // over 256*128
        int k = i >> 7, c = i & 127;
        W1t[(size_t)c * 256 + k] = f2b1(W1[i]);
    } else {
        int i = (b - nbF - 128) * 256 + t;      // over 128*128
        int c = i >> 7, k = i & 127;
        float v = (c < 64) ? W2[(size_t)k * 64 + c]
                           : W2[(size_t)(128 + k) * 64 + (c - 64)];
        W2ct[(size_t)c * 128 + k] = f2b1(v);
    }
}

// ---------------- aggregation layer 1 (bf16 rows of 128) ----------------
// x1[n] = -dinv[n] * sum_e x[src_e] * dinv[src_e]; one wave/node, lane = 1 dword (2 bf16)

__device__ __forceinline__ void gather16(
    const uint* __restrict__ Xu, int lane, int slane, int wlane, int coff,
    float& a0, float& a1)
{
    uint v[16]; float w[16];
    #pragma unroll
    for (int j = 0; j < 16; ++j) {
        int s  = __builtin_amdgcn_readlane(slane, coff + j);
        int wb = __builtin_amdgcn_readlane(wlane, coff + j);
        w[j] = __int_as_float(wb);
        v[j] = Xu[(size_t)s * 64 + lane];
    }
    #pragma unroll
    for (int j = 0; j < 16; ++j) {
        a0 += b2f(v[j] & 0xffffu) * w[j];
        a1 += b2f(v[j] >> 16) * w[j];
    }
}

template <typename CT>
__global__ __launch_bounds__(256) void agg_bf16(
    const ushort* __restrict__ X, const int* __restrict__ rowptr,
    const CT* __restrict__ col, const float* __restrict__ dinv,
    ushort* __restrict__ X1, int nNodes)
{
    int wid  = (blockIdx.x * blockDim.x + threadIdx.x) >> 6;
    int lane = threadIdx.x & 63;
    if (wid >= nNodes) return;
    int e0 = rowptr[wid], e1 = rowptr[wid + 1];
    float sc = -dinv[wid];
    const uint* Xu = reinterpret_cast<const uint*>(X);

    float a0 = 0.f, a1 = 0.f;
    for (int base = e0; base < e1; base += 64) {
        int idx = base + lane;
        int cl = (idx < e1) ? idx : (e1 - 1);
        int s = (int)col[cl];
        float w = (idx < e1) ? dinv[s] : 0.f;
        int wlane = __float_as_int(w);
        int cnt = e1 - base; if (cnt > 64) cnt = 64;
        gather16(Xu, lane, s, wlane, 0, a0, a1);
        if (cnt > 16) gather16(Xu, lane, s, wlane, 16, a0, a1);
        if (cnt > 32) gather16(Xu, lane, s, wlane, 32, a0, a1);
        if (cnt > 48) gather16(Xu, lane, s, wlane, 48, a0, a1);
    }
    uint o = (uint)f2b1(a0 * sc) | ((uint)f2b1(a1 * sc) << 16);
    reinterpret_cast<uint*>(X1)[(size_t)wid * 64 + lane] = o;
}

// ---------------- aggregation layer 2 (bf16 rows of 64, FMA into fp32 out) ----------------
// out[n][l] += -dinv[n] * sum_e Z2[src_e][l] * dinv[src_e]; one wave/node, lane = 1 col

__device__ __forceinline__ void gather16z(
    const ushort* __restrict__ Z, int lane, int slane, int wlane, int coff, float& a0)
{
    uint v[16]; float w[16];
    #pragma unroll
    for (int j = 0; j < 16; ++j) {
        int s  = __builtin_amdgcn_readlane(slane, coff + j);
        int wb = __builtin_amdgcn_readlane(wlane, coff + j);
        w[j] = __int_as_float(wb);
        v[j] = Z[(size_t)s * 64 + lane];
    }
    #pragma unroll
    for (int j = 0; j < 16; ++j)
        a0 += b2f(v[j]) * w[j];
}

template <typename CT>
__global__ __launch_bounds__(256) void agg_add64(
    const ushort* __restrict__ Z2, const int* __restrict__ rowptr,
    const CT* __restrict__ col, const float* __restrict__ dinv,
    float* __restrict__ Y, int nNodes)
{
    int wid  = (blockIdx.x * blockDim.x + threadIdx.x) >> 6;
    int lane = threadIdx.x & 63;
    if (wid >= nNodes) return;
    int e0 = rowptr[wid], e1 = rowptr[wid + 1];
    float sc = -dinv[wid];

    float a0 = 0.f;
    for (int base = e0; base < e1; base += 64) {
        int idx = base + lane;
        int cl = (idx < e1) ? idx : (e1 - 1);
        int s = (int)col[cl];
        float w = (idx < e1) ? dinv[s] : 0.f;
        int wlane = __float_as_int(w);
        int cnt = e1 - base; if (cnt > 64) cnt = 64;
        gather16z(Z2, lane, s, wlane, 0, a0);
        if (cnt > 16) gather16z(Z2, lane, s, wlane, 16, a0);
        if (cnt > 32) gather16z(Z2, lane, s, wlane, 32, a0);
        if (cnt > 48) gather16z(Z2, lane, s, wlane, 48, a0);
    }
    Y[(size_t)wid * 64 + lane] += a0 * sc;
}

// ---------------- MFMA GEMM layer 1: h1 = [XA | XB] @ W1 + b1, K=256, 128 cols, bf16 out ----------------

__global__ __launch_bounds__(256) void gemm_mfma1(
    const ushort* __restrict__ XA, const ushort* __restrict__ XB,
    const ushort* __restrict__ Wt, const float* __restrict__ bias,
    ushort* __restrict__ Y, int nNodes)
{
    constexpr int NCT = 8;  // 128 cols
    int wave = threadIdx.x >> 6, lane = threadIdx.x & 63;
    int r16 = lane & 15, g = lane >> 4;
    int nodeBase = blockIdx.x * 64 + wave * 16;

    int arow = nodeBase + r16;
    if (arow > nNodes - 1) arow = nNodes - 1;
    const ushort* pa0 = XA + (size_t)arow * 128;
    const ushort* pa1 = XB + (size_t)arow * 128;

    f32x4 acc[NCT];
    #pragma unroll
    for (int i = 0; i < NCT; ++i) acc[i] = f32x4{0.f, 0.f, 0.f, 0.f};

    #pragma unroll
    for (int kb = 0; kb < 8; ++kb) {
        const ushort* pa = (kb < 4) ? pa0 : pa1;
        int kk = (kb & 3) * 32 + g * 8;
        bf16x8 a = *reinterpret_cast<const bf16x8*>(pa + kk);
        #pragma unroll
        for (int ct = 0; ct < NCT; ++ct) {
            int colc = ct * 16 + r16;
            bf16x8 b = *reinterpret_cast<const bf16x8*>(Wt + (size_t)colc * 256 + kb * 32 + g * 8);
            acc[ct] = __builtin_amdgcn_mfma_f32_16x16x32_bf16(a, b, acc[ct], 0, 0, 0);
        }
    }

    #pragma unroll
    for (int ct = 0; ct < NCT; ++ct) {
        float bv = bias[ct * 16 + r16];
        #pragma unroll
        for (int r = 0; r < 4; ++r) {
            int orow = nodeBase + g * 4 + r;
            if (orow < nNodes)
                Y[(size_t)orow * 128 + ct * 16 + r16] = f2b1(acc[ct][r] + bv);
        }
    }
}

// ---------------- MFMA GEMM layer 2 fused: [y_top | Z2] = h1 @ W2c, K=128 ----------------
// cols 0-63 -> out fp32 (+bias); cols 64-127 -> Z2 bf16

__global__ __launch_bounds__(256) void gemm_mfma2(
    const ushort* __restrict__ H1, const ushort* __restrict__ W2ct,
    const float* __restrict__ bias, float* __restrict__ Yout,
    ushort* __restrict__ Z2, int nNodes)
{
    constexpr int NCT = 8;  // 128 combined cols
    int wave = threadIdx.x >> 6, lane = threadIdx.x & 63;
    int r16 = lane & 15, g = lane >> 4;
    int nodeBase = blockIdx.x * 64 + wave * 16;

    int arow = nodeBase + r16;
    if (arow > nNodes - 1) arow = nNodes - 1;
    const ushort* pa0 = H1 + (size_t)arow * 128;

    f32x4 acc[NCT];
    #pragma unroll
    for (int i = 0; i < NCT; ++i) acc[i] = f32x4{0.f, 0.f, 0.f, 0.f};

    #pragma unroll
    for (int kb = 0; kb < 4; ++kb) {
        int kk = kb * 32 + g * 8;
        bf16x8 a = *reinterpret_cast<const bf16x8*>(pa0 + kk);
        #pragma unroll
        for (int ct = 0; ct < NCT; ++ct) {
            int colc = ct * 16 + r16;
            bf16x8 b = *reinterpret_cast<const bf16x8*>(W2ct + (size_t)colc * 128 + kk);
            acc[ct] = __builtin_amdgcn_mfma_f32_16x16x32_bf16(a, b, acc[ct], 0, 0, 0);
        }
    }

    #pragma unroll
    for (int ct = 0; ct < NCT; ++ct) {
        float bv = (ct < 4) ? bias[ct * 16 + r16] : 0.f;
        #pragma unroll
        for (int r = 0; r < 4; ++r) {
            int orow = nodeBase + g * 4 + r;
            if (orow < nNodes) {
                if (ct < 4)
                    Yout[(size_t)orow * 64 + ct * 16 + r16] = acc[ct][r] + bv;
                else
                    Z2[(size_t)orow * 64 + (ct - 4) * 16 + r16] = f2b1(acc[ct][r]);
            }
        }
    }
}

// ---------------- host ----------------

extern "C" void kernel_launch(void* const* d_in, const int* in_sizes, int n_in,
                              void* d_out, int out_size, void* d_ws, size_t ws_size,
                              hipStream_t stream)
{
    const float* feats = (const float*)d_in[0];
    const int*   src   = (const int*)d_in[1];
    const int*   dst   = (const int*)d_in[2];
    const float* W1    = (const float*)d_in[3];
    const float* b1    = (const float*)d_in[4];
    const float* W2    = (const float*)d_in[5];
    const float* b2    = (const float*)d_in[6];
    float* out = (float*)d_out;

    const int N = in_sizes[0] / IN_DIM;
    const int E = in_sizes[1];
    const int NB = (N + 1023) / 1024;

    char* ws = (char*)d_ws;
    size_t off = 0;
    int*    deg    = (int*)(ws + off);    off = align256(off + (size_t)N * 4);
    int*    rowptr = (int*)(ws + off);    off = align256(off + (size_t)(N + 1) * 4);
    int*    pre    = (int*)(ws + off);    off = align256(off + (size_t)N * 4);
    int*    bsum   = (int*)(ws + off);    off = align256(off + (size_t)64 * 4);
    int*    rank   = (int*)(ws + off);    off = align256(off + (size_t)E * 4);
    void*   colv   = (void*)(ws + off);   off = align256(off + (size_t)E * 4);  // 2B or 4B per edge
    float*  dinv   = (float*)(ws + off);  off = align256(off + (size_t)N * 4);
    ushort* featb  = (ushort*)(ws + off); off = align256(off + (size_t)N * 128 * 2);
    ushort* x1b    = (ushort*)(ws + off); off = align256(off + (size_t)N * 128 * 2);
    ushort* h1b    = (ushort*)(ws + off); off = align256(off + (size_t)N * 128 * 2);
    ushort* z2b    = (ushort*)(ws + off); off = align256(off + (size_t)N * 64 * 2);
    ushort* W1t    = (ushort*)(ws + off); off = align256(off + (size_t)256 * 128 * 2);
    ushort* W2ct   = (ushort*)(ws + off); off = align256(off + (size_t)128 * 128 * 2);

    // graph prep
    const int n16 = (N * 4 + 15) / 16;   // deg int4 count (deg is 256B-aligned region)
    zero_kernel<<<(n16 + 255) / 256, 256, 0, stream>>>((int4*)deg, n16);
    hist_kernel<<<(E + 255) / 256, 256, 0, stream>>>(dst, deg, rank, E);
    scan_blocks<<<NB, 256, 0, stream>>>(deg, pre, bsum, N);
    scan_bsum<<<1, 64, 0, stream>>>(bsum, NB);
    scan_add<<<(N + 255) / 256, 256, 0, stream>>>(pre, bsum, deg, rowptr, dinv, N, E);

    const bool small = (N <= 65535);
    const int fillBlocks = ((E + 3) / 4 + 255) / 256;
    if (small)
        fill_kernel<ushort><<<fillBlocks, 256, 0, stream>>>(src, dst, rowptr, rank, (ushort*)colv, E);
    else
        fill_kernel<uint><<<fillBlocks, 256, 0, stream>>>(src, dst, rowptr, rank, (uint*)colv, E);

    // fused conversions (independent of graph prep)
    const int nbF = (N * 128) / 1024;
    conv_fused<<<nbF + 128 + 64, 256, 0, stream>>>(feats, featb, nbF, W1, W1t, W2, W2ct);

    const int aggBlocks = (N * 64 + 255) / 256;
    const int gemmBlocks = (N + 63) / 64;

    // layer 1: x1 = -A_hat x ; h1 = [x | x1] @ W1 + b1
    if (small)
        agg_bf16<ushort><<<aggBlocks, 256, 0, stream>>>(featb, rowptr, (const ushort*)colv, dinv, x1b, N);
    else
        agg_bf16<uint><<<aggBlocks, 256, 0, stream>>>(featb, rowptr, (const uint*)colv, dinv, x1b, N);
    gemm_mfma1<<<gemmBlocks, 256, 0, stream>>>(featb, x1b, W1t, b1, h1b, N);

    // layer 2 (reordered): [y_top | Z2] = h1 @ W2c ; out = y_top + (-A_hat Z2)
    gemm_mfma2<<<gemmBlocks, 256, 0, stream>>>(h1b, W2ct, b2, out, z2b, N);
    if (small)
        agg_add64<ushort><<<aggBlocks, 256, 0, stream>>>(z2b, rowptr, (const ushort*)colv, dinv, out, N);
    else
        agg_add64<uint><<<aggBlocks, 256, 0, stream>>>(z2b, rowptr, (const uint*)colv, dinv, out, N);
}

// Round 7
// 151.333 us; speedup vs baseline: 3.4125x; 1.2049x over previous
//
#include <hip/hip_runtime.h>

#define IN_DIM  128

typedef __bf16 bf16x8 __attribute__((ext_vector_type(8)));
typedef float  f32x4  __attribute__((ext_vector_type(4)));

static inline size_t align256(size_t x) { return (x + 255) & ~size_t(255); }

// ---------- bf16 helpers (RNE) ----------
__device__ __forceinline__ ushort f2b1(float f) {
    union { float f; uint u; } c; c.f = f;
    uint u = c.u;
    uint r = (u + 0x7FFFu + ((u >> 16) & 1u)) >> 16;
    return (ushort)r;
}
__device__ __forceinline__ float b2f(uint v16) {
    union { uint u; float f; } c; c.u = v16 << 16; return c.f;
}

// ---------------- graph prep ----------------

__global__ void zero_kernel(int4* __restrict__ p, int n16) {
    int i = blockIdx.x * blockDim.x + threadIdx.x;
    if (i < n16) p[i] = make_int4(0, 0, 0, 0);
}

// histogram + per-edge rank (order within its dst bucket)
__global__ void hist_kernel(const int* __restrict__ dst, int* __restrict__ deg,
                            int* __restrict__ rank, int E) {
    int e = blockIdx.x * blockDim.x + threadIdx.x;
    if (e < E) rank[e] = atomicAdd(&deg[dst[e]], 1);
}

// phase A: per-block (1024 elems) exclusive prescan + block sums
__global__ __launch_bounds__(256) void scan_blocks(const int* __restrict__ deg,
                                                   int* __restrict__ pre,
                                                   int* __restrict__ bsum, int n) {
    __shared__ int sh[256];
    int t = threadIdx.x;
    int base = blockIdx.x * 1024 + t * 4;
    int v0 = 0, v1 = 0, v2 = 0, v3 = 0;
    if (base + 3 < n) {
        int4 v = *reinterpret_cast<const int4*>(deg + base);
        v0 = v.x; v1 = v.y; v2 = v.z; v3 = v.w;
    } else {
        if (base     < n) v0 = deg[base];
        if (base + 1 < n) v1 = deg[base + 1];
        if (base + 2 < n) v2 = deg[base + 2];
        if (base + 3 < n) v3 = deg[base + 3];
    }
    int s = v0 + v1 + v2 + v3;
    sh[t] = s;
    __syncthreads();
    for (int off = 1; off < 256; off <<= 1) {
        int x = (t >= off) ? sh[t - off] : 0;
        __syncthreads();
        sh[t] += x;
        __syncthreads();
    }
    int excl = sh[t] - s;
    if (t == 255) bsum[blockIdx.x] = sh[255];
    if (base     < n) pre[base]     = excl;
    if (base + 1 < n) pre[base + 1] = excl + v0;
    if (base + 2 < n) pre[base + 2] = excl + v0 + v1;
    if (base + 3 < n) pre[base + 3] = excl + v0 + v1 + v2;
}

// phase B: exclusive scan of block sums (nb <= 64) with one wave
__global__ void scan_bsum(int* __restrict__ bsum, int nb) {
    int l = threadIdx.x;  // 64 lanes
    int orig = (l < nb) ? bsum[l] : 0;
    int v = orig;
    for (int off = 1; off < 64; off <<= 1) {
        int u = __shfl_up(v, off);
        if (l >= off) v += u;
    }
    if (l < nb) bsum[l] = v - orig;
}

// phase C: add block offsets + compute dinv
__global__ void scan_add(const int* __restrict__ pre, const int* __restrict__ bsum,
                         const int* __restrict__ deg,
                         int* __restrict__ rowptr, float* __restrict__ dinv,
                         int n, int E) {
    int i = blockIdx.x * blockDim.x + threadIdx.x;
    if (i < n) {
        rowptr[i] = pre[i] + bsum[i >> 10];
        int d = deg[i]; if (d < 1) d = 1;
        dinv[i] = rsqrtf((float)d);
    }
    if (i == 0) rowptr[n] = E;
}

// fill CSR col (no atomics): col[rowptr[dst]+rank] = src ; 4 edges/thread
template <typename CT>
__global__ __launch_bounds__(256) void fill_kernel(
    const int* __restrict__ src, const int* __restrict__ dst,
    const int* __restrict__ rowptr, const int* __restrict__ rank,
    CT* __restrict__ col, int E)
{
    int e0 = (blockIdx.x * blockDim.x + threadIdx.x) * 4;
    if (e0 + 3 < E) {
        int4 d4 = *reinterpret_cast<const int4*>(dst + e0);
        int4 r4 = *reinterpret_cast<const int4*>(rank + e0);
        int4 s4 = *reinterpret_cast<const int4*>(src + e0);
        int p0 = rowptr[d4.x] + r4.x;
        int p1 = rowptr[d4.y] + r4.y;
        int p2 = rowptr[d4.z] + r4.z;
        int p3 = rowptr[d4.w] + r4.w;
        col[p0] = (CT)s4.x;
        col[p1] = (CT)s4.y;
        col[p2] = (CT)s4.z;
        col[p3] = (CT)s4.w;
    } else {
        for (int e = e0; e < E; ++e)
            col[rowptr[dst[e]] + rank[e]] = (CT)src[e];
    }
}

// ---------------- fused conversions ----------------
// feats->bf16; W1->W1t [128 cols][256 k]; W2->W2ct combined [128 cols][128 k]
// W2ct col c<64: y_top col c -> W2[k][c]; col c>=64: z2 col (c-64) -> W2[128+k][c-64]

__global__ __launch_bounds__(256) void conv_fused(
    const float* __restrict__ feats, ushort* __restrict__ featb, int nbF,
    const float* __restrict__ W1, ushort* __restrict__ W1t,
    const float* __restrict__ W2, ushort* __restrict__ W2ct)
{
    int b = blockIdx.x, t = threadIdx.x;
    if (b < nbF) {
        size_t i = ((size_t)b * 256 + t) * 4;
        float4 v = *reinterpret_cast<const float4*>(feats + i);
        ushort4 o;
        o.x = f2b1(v.x); o.y = f2b1(v.y); o.z = f2b1(v.z); o.w = f2b1(v.w);
        *reinterpret_cast<ushort4*>(featb + i) = o;
    } else if (b < nbF + 128) {
        int i = (b - nbF) * 256 + t;            // over 256*128
        int k = i >> 7, c = i & 127;
        W1t[(size_t)c * 256 + k] = f2b1(W1[i]);
    } else {
        int i = (b - nbF - 128) * 256 + t;      // over 128*128
        int c = i >> 7, k = i & 127;
        float v = (c < 64) ? W2[(size_t)k * 64 + c]
                           : W2[(size_t)(128 + k) * 64 + (c - 64)];
        W2ct[(size_t)c * 128 + k] = f2b1(v);
    }
}

// ---------------- aggregation layer 1 (bf16 rows of 128) ----------------
// x1[n] = -dinv[n] * sum_e x[src_e] * dinv[src_e]; one wave/node, lane = 1 dword (2 bf16)

__device__ __forceinline__ void gather16(
    const uint* __restrict__ Xu, int lane, int slane, int wlane, int coff,
    float& a0, float& a1)
{
    uint v[16]; float w[16];
    #pragma unroll
    for (int j = 0; j < 16; ++j) {
        int s  = __builtin_amdgcn_readlane(slane, coff + j);
        int wb = __builtin_amdgcn_readlane(wlane, coff + j);
        w[j] = __int_as_float(wb);
        v[j] = Xu[(size_t)s * 64 + lane];
    }
    #pragma unroll
    for (int j = 0; j < 16; ++j) {
        a0 += b2f(v[j] & 0xffffu) * w[j];
        a1 += b2f(v[j] >> 16) * w[j];
    }
}

template <typename CT>
__global__ __launch_bounds__(256) void agg_bf16(
    const ushort* __restrict__ X, const int* __restrict__ rowptr,
    const CT* __restrict__ col, const float* __restrict__ dinv,
    ushort* __restrict__ X1, int nNodes)
{
    int wid  = (blockIdx.x * blockDim.x + threadIdx.x) >> 6;
    int lane = threadIdx.x & 63;
    if (wid >= nNodes) return;
    int e0 = rowptr[wid], e1 = rowptr[wid + 1];
    float sc = -dinv[wid];
    const uint* Xu = reinterpret_cast<const uint*>(X);

    float a0 = 0.f, a1 = 0.f;
    for (int base = e0; base < e1; base += 64) {
        int idx = base + lane;
        int cl = (idx < e1) ? idx : (e1 - 1);
        int s = (int)col[cl];
        float w = (idx < e1) ? dinv[s] : 0.f;
        int wlane = __float_as_int(w);
        int cnt = e1 - base; if (cnt > 64) cnt = 64;
        gather16(Xu, lane, s, wlane, 0, a0, a1);
        if (cnt > 16) gather16(Xu, lane, s, wlane, 16, a0, a1);
        if (cnt > 32) gather16(Xu, lane, s, wlane, 32, a0, a1);
        if (cnt > 48) gather16(Xu, lane, s, wlane, 48, a0, a1);
    }
    uint o = (uint)f2b1(a0 * sc) | ((uint)f2b1(a1 * sc) << 16);
    reinterpret_cast<uint*>(X1)[(size_t)wid * 64 + lane] = o;
}

// ---------------- aggregation layer 2 (bf16 rows of 64, FMA into fp32 out) ----------------

__device__ __forceinline__ void gather16z(
    const ushort* __restrict__ Z, int lane, int slane, int wlane, int coff, float& a0)
{
    uint v[16]; float w[16];
    #pragma unroll
    for (int j = 0; j < 16; ++j) {
        int s  = __builtin_amdgcn_readlane(slane, coff + j);
        int wb = __builtin_amdgcn_readlane(wlane, coff + j);
        w[j] = __int_as_float(wb);
        v[j] = Z[(size_t)s * 64 + lane];
    }
    #pragma unroll
    for (int j = 0; j < 16; ++j)
        a0 += b2f(v[j]) * w[j];
}

template <typename CT>
__global__ __launch_bounds__(256) void agg_add64(
    const ushort* __restrict__ Z2, const int* __restrict__ rowptr,
    const CT* __restrict__ col, const float* __restrict__ dinv,
    float* __restrict__ Y, int nNodes)
{
    int wid  = (blockIdx.x * blockDim.x + threadIdx.x) >> 6;
    int lane = threadIdx.x & 63;
    if (wid >= nNodes) return;
    int e0 = rowptr[wid], e1 = rowptr[wid + 1];
    float sc = -dinv[wid];

    float a0 = 0.f;
    for (int base = e0; base < e1; base += 64) {
        int idx = base + lane;
        int cl = (idx < e1) ? idx : (e1 - 1);
        int s = (int)col[cl];
        float w = (idx < e1) ? dinv[s] : 0.f;
        int wlane = __float_as_int(w);
        int cnt = e1 - base; if (cnt > 64) cnt = 64;
        gather16z(Z2, lane, s, wlane, 0, a0);
        if (cnt > 16) gather16z(Z2, lane, s, wlane, 16, a0);
        if (cnt > 32) gather16z(Z2, lane, s, wlane, 32, a0);
        if (cnt > 48) gather16z(Z2, lane, s, wlane, 48, a0);
    }
    Y[(size_t)wid * 64 + lane] += a0 * sc;
}

// ---------------- MFMA GEMM layer 1: h1 = [XA | XB] @ W1 + b1 ----------------
// W1t staged in LDS (64KB, XOR-swizzled). Block = 4 waves x 32 nodes = 128 nodes.

__global__ __launch_bounds__(256) void gemm_mfma1(
    const ushort* __restrict__ XA, const ushort* __restrict__ XB,
    const ushort* __restrict__ Wt, const float* __restrict__ bias,
    ushort* __restrict__ Y, int nNodes)
{
    __shared__ ushort wlds[128 * 256];   // 64 KB: [col][512B row], swizzled
    int t = threadIdx.x;

    // stage: 4096 chunks of 16B; swizzle byte-offset within row by ((col&7)<<4)
    #pragma unroll
    for (int it = 0; it < 16; ++it) {
        int i = it * 256 + t;
        int c = i >> 5;                 // col 0..127
        int o = (i & 31) << 4;          // byte offset 0..496
        bf16x8 v = *reinterpret_cast<const bf16x8*>(Wt + ((size_t)c << 8) + (o >> 1));
        *reinterpret_cast<bf16x8*>((char*)wlds + ((size_t)c << 9) + (o ^ ((c & 7) << 4))) = v;
    }
    __syncthreads();

    int wave = t >> 6, lane = t & 63;
    int r16 = lane & 15, g = lane >> 4;
    int nodeBase = blockIdx.x * 128 + wave * 32;

    int arow0 = nodeBase + r16;       if (arow0 > nNodes - 1) arow0 = nNodes - 1;
    int arow1 = nodeBase + 16 + r16;  if (arow1 > nNodes - 1) arow1 = nNodes - 1;
    const ushort* pA0 = XA + (size_t)arow0 * 128;
    const ushort* pA1 = XA + (size_t)arow1 * 128;
    const ushort* pB0 = XB + (size_t)arow0 * 128;
    const ushort* pB1 = XB + (size_t)arow1 * 128;

    f32x4 acc0[8], acc1[8];
    #pragma unroll
    for (int i = 0; i < 8; ++i) { acc0[i] = f32x4{0,0,0,0}; acc1[i] = f32x4{0,0,0,0}; }

    #pragma unroll
    for (int kb = 0; kb < 8; ++kb) {
        int kk = (kb & 3) * 32 + g * 8;
        bf16x8 a0 = *reinterpret_cast<const bf16x8*>(((kb < 4) ? pA0 : pB0) + kk);
        bf16x8 a1 = *reinterpret_cast<const bf16x8*>(((kb < 4) ? pA1 : pB1) + kk);
        int o = kb * 64 + g * 16;
        #pragma unroll
        for (int ct = 0; ct < 8; ++ct) {
            int c = ct * 16 + r16;
            bf16x8 b = *reinterpret_cast<const bf16x8*>(
                (const char*)wlds + ((size_t)c << 9) + (o ^ ((c & 7) << 4)));
            acc0[ct] = __builtin_amdgcn_mfma_f32_16x16x32_bf16(a0, b, acc0[ct], 0, 0, 0);
            acc1[ct] = __builtin_amdgcn_mfma_f32_16x16x32_bf16(a1, b, acc1[ct], 0, 0, 0);
        }
    }

    #pragma unroll
    for (int ct = 0; ct < 8; ++ct) {
        float bv = bias[ct * 16 + r16];
        #pragma unroll
        for (int r = 0; r < 4; ++r) {
            int orow0 = nodeBase + g * 4 + r;
            int orow1 = orow0 + 16;
            if (orow0 < nNodes) Y[(size_t)orow0 * 128 + ct * 16 + r16] = f2b1(acc0[ct][r] + bv);
            if (orow1 < nNodes) Y[(size_t)orow1 * 128 + ct * 16 + r16] = f2b1(acc1[ct][r] + bv);
        }
    }
}

// ---------------- MFMA GEMM layer 2 fused: [y_top | Z2] = h1 @ W2c, K=128 ----------------
// W2ct staged in LDS (32KB, swizzled). cols 0-63 -> out fp32 (+bias); 64-127 -> Z2 bf16.

__global__ __launch_bounds__(256) void gemm_mfma2(
    const ushort* __restrict__ H1, const ushort* __restrict__ W2ct,
    const float* __restrict__ bias, float* __restrict__ Yout,
    ushort* __restrict__ Z2, int nNodes)
{
    __shared__ ushort wlds[128 * 128];   // 32 KB: [col][256B row], swizzled
    int t = threadIdx.x;

    #pragma unroll
    for (int it = 0; it < 8; ++it) {
        int i = it * 256 + t;           // 2048 chunks of 16B
        int c = i >> 4;                 // col 0..127
        int o = (i & 15) << 4;          // byte offset 0..240
        bf16x8 v = *reinterpret_cast<const bf16x8*>(W2ct + ((size_t)c << 7) + (o >> 1));
        *reinterpret_cast<bf16x8*>((char*)wlds + ((size_t)c << 8) + (o ^ ((c & 7) << 4))) = v;
    }
    __syncthreads();

    int wave = t >> 6, lane = t & 63;
    int r16 = lane & 15, g = lane >> 4;
    int nodeBase = blockIdx.x * 128 + wave * 32;

    int arow0 = nodeBase + r16;       if (arow0 > nNodes - 1) arow0 = nNodes - 1;
    int arow1 = nodeBase + 16 + r16;  if (arow1 > nNodes - 1) arow1 = nNodes - 1;
    const ushort* p0 = H1 + (size_t)arow0 * 128;
    const ushort* p1 = H1 + (size_t)arow1 * 128;

    f32x4 acc0[8], acc1[8];
    #pragma unroll
    for (int i = 0; i < 8; ++i) { acc0[i] = f32x4{0,0,0,0}; acc1[i] = f32x4{0,0,0,0}; }

    #pragma unroll
    for (int kb = 0; kb < 4; ++kb) {
        int kk = kb * 32 + g * 8;
        bf16x8 a0 = *reinterpret_cast<const bf16x8*>(p0 + kk);
        bf16x8 a1 = *reinterpret_cast<const bf16x8*>(p1 + kk);
        int o = kb * 64 + g * 16;
        #pragma unroll
        for (int ct = 0; ct < 8; ++ct) {
            int c = ct * 16 + r16;
            bf16x8 b = *reinterpret_cast<const bf16x8*>(
                (const char*)wlds + ((size_t)c << 8) + (o ^ ((c & 7) << 4)));
            acc0[ct] = __builtin_amdgcn_mfma_f32_16x16x32_bf16(a0, b, acc0[ct], 0, 0, 0);
            acc1[ct] = __builtin_amdgcn_mfma_f32_16x16x32_bf16(a1, b, acc1[ct], 0, 0, 0);
        }
    }

    #pragma unroll
    for (int ct = 0; ct < 8; ++ct) {
        float bv = (ct < 4) ? bias[ct * 16 + r16] : 0.f;
        #pragma unroll
        for (int r = 0; r < 4; ++r) {
            int orow0 = nodeBase + g * 4 + r;
            int orow1 = orow0 + 16;
            if (ct < 4) {
                if (orow0 < nNodes) Yout[(size_t)orow0 * 64 + ct * 16 + r16] = acc0[ct][r] + bv;
                if (orow1 < nNodes) Yout[(size_t)orow1 * 64 + ct * 16 + r16] = acc1[ct][r] + bv;
            } else {
                if (orow0 < nNodes) Z2[(size_t)orow0 * 64 + (ct - 4) * 16 + r16] = f2b1(acc0[ct][r]);
                if (orow1 < nNodes) Z2[(size_t)orow1 * 64 + (ct - 4) * 16 + r16] = f2b1(acc1[ct][r]);
            }
        }
    }
}

// ---------------- host ----------------

extern "C" void kernel_launch(void* const* d_in, const int* in_sizes, int n_in,
                              void* d_out, int out_size, void* d_ws, size_t ws_size,
                              hipStream_t stream)
{
    const float* feats = (const float*)d_in[0];
    const int*   src   = (const int*)d_in[1];
    const int*   dst   = (const int*)d_in[2];
    const float* W1    = (const float*)d_in[3];
    const float* b1    = (const float*)d_in[4];
    const float* W2    = (const float*)d_in[5];
    const float* b2    = (const float*)d_in[6];
    float* out = (float*)d_out;

    const int N = in_sizes[0] / IN_DIM;
    const int E = in_sizes[1];
    const int NB = (N + 1023) / 1024;

    char* ws = (char*)d_ws;
    size_t off = 0;
    int*    deg    = (int*)(ws + off);    off = align256(off + (size_t)N * 4);
    int*    rowptr = (int*)(ws + off);    off = align256(off + (size_t)(N + 1) * 4);
    int*    pre    = (int*)(ws + off);    off = align256(off + (size_t)N * 4);
    int*    bsum   = (int*)(ws + off);    off = align256(off + (size_t)64 * 4);
    int*    rank   = (int*)(ws + off);    off = align256(off + (size_t)E * 4);
    void*   colv   = (void*)(ws + off);   off = align256(off + (size_t)E * 4);  // 2B or 4B per edge
    float*  dinv   = (float*)(ws + off);  off = align256(off + (size_t)N * 4);
    ushort* featb  = (ushort*)(ws + off); off = align256(off + (size_t)N * 128 * 2);
    ushort* x1b    = (ushort*)(ws + off); off = align256(off + (size_t)N * 128 * 2);
    ushort* h1b    = (ushort*)(ws + off); off = align256(off + (size_t)N * 128 * 2);
    ushort* z2b    = (ushort*)(ws + off); off = align256(off + (size_t)N * 64 * 2);
    ushort* W1t    = (ushort*)(ws + off); off = align256(off + (size_t)256 * 128 * 2);
    ushort* W2ct   = (ushort*)(ws + off); off = align256(off + (size_t)128 * 128 * 2);

    // graph prep
    const int n16 = (N * 4 + 15) / 16;
    zero_kernel<<<(n16 + 255) / 256, 256, 0, stream>>>((int4*)deg, n16);
    hist_kernel<<<(E + 255) / 256, 256, 0, stream>>>(dst, deg, rank, E);
    scan_blocks<<<NB, 256, 0, stream>>>(deg, pre, bsum, N);
    scan_bsum<<<1, 64, 0, stream>>>(bsum, NB);
    scan_add<<<(N + 255) / 256, 256, 0, stream>>>(pre, bsum, deg, rowptr, dinv, N, E);

    const bool small = (N <= 65535);
    const int fillBlocks = ((E + 3) / 4 + 255) / 256;
    if (small)
        fill_kernel<ushort><<<fillBlocks, 256, 0, stream>>>(src, dst, rowptr, rank, (ushort*)colv, E);
    else
        fill_kernel<uint><<<fillBlocks, 256, 0, stream>>>(src, dst, rowptr, rank, (uint*)colv, E);

    // fused conversions (independent of graph prep)
    const int nbF = (N * 128) / 1024;
    conv_fused<<<nbF + 128 + 64, 256, 0, stream>>>(feats, featb, nbF, W1, W1t, W2, W2ct);

    const int aggBlocks = (N * 64 + 255) / 256;
    const int gemmBlocks = (N + 127) / 128;

    // layer 1: x1 = -A_hat x ; h1 = [x | x1] @ W1 + b1
    if (small)
        agg_bf16<ushort><<<aggBlocks, 256, 0, stream>>>(featb, rowptr, (const ushort*)colv, dinv, x1b, N);
    else
        agg_bf16<uint><<<aggBlocks, 256, 0, stream>>>(featb, rowptr, (const uint*)colv, dinv, x1b, N);
    gemm_mfma1<<<gemmBlocks, 256, 0, stream>>>(featb, x1b, W1t, b1, h1b, N);

    // layer 2 (reordered): [y_top | Z2] = h1 @ W2c ; out = y_top + (-A_hat Z2)
    gemm_mfma2<<<gemmBlocks, 256, 0, stream>>>(h1b, W2ct, b2, out, z2b, N);
    if (small)
        agg_add64<ushort><<<aggBlocks, 256, 0, stream>>>(z2b, rowptr, (const ushort*)colv, dinv, out, N);
    else
        agg_add64<uint><<<aggBlocks, 256, 0, stream>>>(z2b, rowptr, (const uint*)colv, dinv, out, N);
}

// Round 8
// 145.920 us; speedup vs baseline: 3.5391x; 1.0371x over previous
//
#include <hip/hip_runtime.h>

#define IN_DIM  128

typedef __bf16 bf16x8 __attribute__((ext_vector_type(8)));
typedef float  f32x4  __attribute__((ext_vector_type(4)));

static inline size_t align256(size_t x) { return (x + 255) & ~size_t(255); }

// ---------- bf16 helpers (RNE) ----------
__device__ __forceinline__ ushort f2b1(float f) {
    union { float f; uint u; } c; c.f = f;
    uint u = c.u;
    uint r = (u + 0x7FFFu + ((u >> 16) & 1u)) >> 16;
    return (ushort)r;
}
__device__ __forceinline__ float lo_bf(uint v) {   // low bf16 -> f32
    union { uint u; float f; } c; c.u = v << 16; return c.f;
}
__device__ __forceinline__ float hi_bf(uint v) {   // high bf16 -> f32
    union { uint u; float f; } c; c.u = v & 0xffff0000u; return c.f;
}

// ---------------- graph prep ----------------

__global__ void zero_kernel(int4* __restrict__ p, int n16) {
    int i = blockIdx.x * blockDim.x + threadIdx.x;
    if (i < n16) p[i] = make_int4(0, 0, 0, 0);
}

// histogram + per-edge rank (order within its dst bucket)
__global__ void hist_kernel(const int* __restrict__ dst, int* __restrict__ deg,
                            int* __restrict__ rank, int E) {
    int e = blockIdx.x * blockDim.x + threadIdx.x;
    if (e < E) rank[e] = atomicAdd(&deg[dst[e]], 1);
}

// phase A: per-block (1024 elems) exclusive prescan + block sums
__global__ __launch_bounds__(256) void scan_blocks(const int* __restrict__ deg,
                                                   int* __restrict__ pre,
                                                   int* __restrict__ bsum, int n) {
    __shared__ int sh[256];
    int t = threadIdx.x;
    int base = blockIdx.x * 1024 + t * 4;
    int v0 = 0, v1 = 0, v2 = 0, v3 = 0;
    if (base + 3 < n) {
        int4 v = *reinterpret_cast<const int4*>(deg + base);
        v0 = v.x; v1 = v.y; v2 = v.z; v3 = v.w;
    } else {
        if (base     < n) v0 = deg[base];
        if (base + 1 < n) v1 = deg[base + 1];
        if (base + 2 < n) v2 = deg[base + 2];
        if (base + 3 < n) v3 = deg[base + 3];
    }
    int s = v0 + v1 + v2 + v3;
    sh[t] = s;
    __syncthreads();
    for (int off = 1; off < 256; off <<= 1) {
        int x = (t >= off) ? sh[t - off] : 0;
        __syncthreads();
        sh[t] += x;
        __syncthreads();
    }
    int excl = sh[t] - s;
    if (t == 255) bsum[blockIdx.x] = sh[255];
    if (base     < n) pre[base]     = excl;
    if (base + 1 < n) pre[base + 1] = excl + v0;
    if (base + 2 < n) pre[base + 2] = excl + v0 + v1;
    if (base + 3 < n) pre[base + 3] = excl + v0 + v1 + v2;
}

// phase B+C fused: every block re-scans bsum (<=64 entries) in wave 0, then adds
__global__ __launch_bounds__(256) void scan_add(
    const int* __restrict__ pre, const int* __restrict__ bsum,
    const int* __restrict__ deg,
    int* __restrict__ rowptr, float* __restrict__ dinv,
    int n, int E, int nb)
{
    __shared__ int sb[64];
    int t = threadIdx.x;
    if (t < 64) {
        int orig = (t < nb) ? bsum[t] : 0;
        int v = orig;
        for (int off = 1; off < 64; off <<= 1) {
            int u = __shfl_up(v, off);
            if (t >= off) v += u;
        }
        sb[t] = v - orig;   // exclusive
    }
    __syncthreads();
    int i = blockIdx.x * blockDim.x + t;
    if (i < n) {
        rowptr[i] = pre[i] + sb[i >> 10];
        int d = deg[i]; if (d < 1) d = 1;
        dinv[i] = rsqrtf((float)d);
    }
    if (i == 0) rowptr[n] = E;
}

// ---------------- phase2: fill CSR (no atomics) + conversions, one dispatch ----------------
// fill: col[rowptr[dst]+rank] = src, 4 edges/thread
// conv: featb = bf16(x); featbs = bf16(x*dinv) [N+1 rows, row N = 0]
//       W1t [128 cols][256 k]; W2ct [128 cols][128 k] (cols 0-63: y_top, 64-127: z2)
//       + zero pad rows of featbs and z2s

template <typename CT>
__global__ __launch_bounds__(256) void phase2_kernel(
    const int* __restrict__ src, const int* __restrict__ dst,
    const int* __restrict__ rowptr, const int* __restrict__ rank,
    CT* __restrict__ col, int E, int fillBlocks,
    const float* __restrict__ feats, const float* __restrict__ dinv,
    ushort* __restrict__ featb, ushort* __restrict__ featbs,
    ushort* __restrict__ z2s, int N, int nbF,
    const float* __restrict__ W1, ushort* __restrict__ W1t,
    const float* __restrict__ W2, ushort* __restrict__ W2ct)
{
    int b = blockIdx.x, t = threadIdx.x;
    if (b < fillBlocks) {
        int e0 = (b * 256 + t) * 4;
        if (e0 + 3 < E) {
            int4 d4 = *reinterpret_cast<const int4*>(dst + e0);
            int4 r4 = *reinterpret_cast<const int4*>(rank + e0);
            int4 s4 = *reinterpret_cast<const int4*>(src + e0);
            col[rowptr[d4.x] + r4.x] = (CT)s4.x;
            col[rowptr[d4.y] + r4.y] = (CT)s4.y;
            col[rowptr[d4.z] + r4.z] = (CT)s4.z;
            col[rowptr[d4.w] + r4.w] = (CT)s4.w;
        } else {
            for (int e = e0; e < E; ++e)
                col[rowptr[dst[e]] + rank[e]] = (CT)src[e];
        }
        return;
    }
    int b2 = b - fillBlocks;
    if (b2 < nbF) {
        size_t i4 = (size_t)b2 * 256 + t;         // float4 index
        if (i4 < (size_t)N * 32) {
            size_t i = i4 * 4;
            float4 v = *reinterpret_cast<const float4*>(feats + i);
            float dv = dinv[i >> 7];              // 4 consecutive floats share a node
            ushort4 o, os;
            o.x  = f2b1(v.x);      o.y  = f2b1(v.y);      o.z  = f2b1(v.z);      o.w  = f2b1(v.w);
            os.x = f2b1(v.x * dv); os.y = f2b1(v.y * dv); os.z = f2b1(v.z * dv); os.w = f2b1(v.w * dv);
            *reinterpret_cast<ushort4*>(featb  + i) = o;
            *reinterpret_cast<ushort4*>(featbs + i) = os;
        }
    } else if (b2 < nbF + 128) {
        if (b2 == nbF) {  // zero pad rows (row N of featbs: 128 ushorts; row N of z2s: 64)
            if (t < 32) *reinterpret_cast<uint2*>(featbs + (size_t)N * 128 + t * 4) = make_uint2(0, 0);
            else if (t < 48) *reinterpret_cast<uint2*>(z2s + (size_t)N * 64 + (t - 32) * 4) = make_uint2(0, 0);
        }
        int i = (b2 - nbF) * 256 + t;             // over 256*128
        int k = i >> 7, c = i & 127;
        W1t[(size_t)c * 256 + k] = f2b1(W1[i]);
    } else {
        int i = (b2 - nbF - 128) * 256 + t;       // over 128*128
        int c = i >> 7, k = i & 127;
        float v = (c < 64) ? W2[(size_t)k * 64 + c]
                           : W2[(size_t)(128 + k) * 64 + (c - 64)];
        W2ct[(size_t)c * 128 + k] = f2b1(v);
    }
}

// ---------------- aggregation layer 1: x1[n] = -dinv[n] * sum_e featbs[src_e] ----------------
// one wave/node; lane = 1 dword (2 bf16); padding edges -> zero row (index N)

__device__ __forceinline__ void sum16(
    const uint* __restrict__ Xu, int lane, int slane, int coff,
    float& a0, float& a1)
{
    uint v[16];
    #pragma unroll
    for (int j = 0; j < 16; ++j) {
        int s = __builtin_amdgcn_readlane(slane, coff + j);
        v[j] = Xu[(uint)(s * 64 + lane)];
    }
    #pragma unroll
    for (int j = 0; j < 16; ++j) {
        a0 += lo_bf(v[j]);
        a1 += hi_bf(v[j]);
    }
}

template <typename CT>
__global__ __launch_bounds__(256) void agg_sum128(
    const ushort* __restrict__ Xs, const int* __restrict__ rowptr,
    const CT* __restrict__ col, const float* __restrict__ dinv,
    ushort* __restrict__ X1, int nNodes)
{
    int wid  = (blockIdx.x * blockDim.x + threadIdx.x) >> 6;
    int lane = threadIdx.x & 63;
    if (wid >= nNodes) return;
    wid = __builtin_amdgcn_readfirstlane(wid);
    int e0 = rowptr[wid], e1 = rowptr[wid + 1];
    float sc = -dinv[wid];
    const uint* Xu = reinterpret_cast<const uint*>(Xs);

    float a0 = 0.f, a1 = 0.f;
    for (int base = e0; base < e1; base += 64) {
        int idx = base + lane;
        int s = (idx < e1) ? (int)col[(idx < e1) ? idx : e0] : nNodes;  // pad -> zero row
        int cnt = e1 - base; if (cnt > 64) cnt = 64;
        sum16(Xu, lane, s, 0, a0, a1);
        if (cnt > 16) sum16(Xu, lane, s, 16, a0, a1);
        if (cnt > 32) sum16(Xu, lane, s, 32, a0, a1);
        if (cnt > 48) sum16(Xu, lane, s, 48, a0, a1);
    }
    uint o = (uint)f2b1(a0 * sc) | ((uint)f2b1(a1 * sc) << 16);
    reinterpret_cast<uint*>(X1)[(uint)(wid * 64 + lane)] = o;
}

// ---------------- aggregation layer 2: out[n] += -dinv[n] * sum_e z2s[src_e] ----------------

__device__ __forceinline__ void sum16z(
    const ushort* __restrict__ Z, int lane, int slane, int coff, float& a0)
{
    ushort v[16];
    #pragma unroll
    for (int j = 0; j < 16; ++j) {
        int s = __builtin_amdgcn_readlane(slane, coff + j);
        v[j] = Z[(uint)(s * 64 + lane)];
    }
    #pragma unroll
    for (int j = 0; j < 16; ++j)
        a0 += lo_bf((uint)v[j]);
}

template <typename CT>
__global__ __launch_bounds__(256) void agg_sum64(
    const ushort* __restrict__ Z2, const int* __restrict__ rowptr,
    const CT* __restrict__ col, const float* __restrict__ dinv,
    float* __restrict__ Y, int nNodes)
{
    int wid  = (blockIdx.x * blockDim.x + threadIdx.x) >> 6;
    int lane = threadIdx.x & 63;
    if (wid >= nNodes) return;
    wid = __builtin_amdgcn_readfirstlane(wid);
    int e0 = rowptr[wid], e1 = rowptr[wid + 1];
    float sc = -dinv[wid];

    float a0 = 0.f;
    for (int base = e0; base < e1; base += 64) {
        int idx = base + lane;
        int s = (idx < e1) ? (int)col[(idx < e1) ? idx : e0] : nNodes;
        int cnt = e1 - base; if (cnt > 64) cnt = 64;
        sum16z(Z2, lane, s, 0, a0);
        if (cnt > 16) sum16z(Z2, lane, s, 16, a0);
        if (cnt > 32) sum16z(Z2, lane, s, 32, a0);
        if (cnt > 48) sum16z(Z2, lane, s, 48, a0);
    }
    Y[(uint)(wid * 64 + lane)] += a0 * sc;
}

// ---------------- MFMA GEMM layer 1: h1 = [XA | XB] @ W1 + b1 ----------------
// W1t staged in LDS (64KB, XOR-swizzled). Block = 4 waves x 32 nodes = 128 nodes.

__global__ __launch_bounds__(256) void gemm_mfma1(
    const ushort* __restrict__ XA, const ushort* __restrict__ XB,
    const ushort* __restrict__ Wt, const float* __restrict__ bias,
    ushort* __restrict__ Y, int nNodes)
{
    __shared__ ushort wlds[128 * 256];   // 64 KB: [col][512B row], swizzled
    int t = threadIdx.x;

    #pragma unroll
    for (int it = 0; it < 16; ++it) {
        int i = it * 256 + t;
        int c = i >> 5;                 // col 0..127
        int o = (i & 31) << 4;          // byte offset 0..496
        bf16x8 v = *reinterpret_cast<const bf16x8*>(Wt + ((size_t)c << 8) + (o >> 1));
        *reinterpret_cast<bf16x8*>((char*)wlds + ((size_t)c << 9) + (o ^ ((c & 7) << 4))) = v;
    }
    __syncthreads();

    int wave = t >> 6, lane = t & 63;
    int r16 = lane & 15, g = lane >> 4;
    int nodeBase = blockIdx.x * 128 + wave * 32;

    int arow0 = nodeBase + r16;       if (arow0 > nNodes - 1) arow0 = nNodes - 1;
    int arow1 = nodeBase + 16 + r16;  if (arow1 > nNodes - 1) arow1 = nNodes - 1;
    const ushort* pA0 = XA + (size_t)arow0 * 128;
    const ushort* pA1 = XA + (size_t)arow1 * 128;
    const ushort* pB0 = XB + (size_t)arow0 * 128;
    const ushort* pB1 = XB + (size_t)arow1 * 128;

    f32x4 acc0[8], acc1[8];
    #pragma unroll
    for (int i = 0; i < 8; ++i) { acc0[i] = f32x4{0,0,0,0}; acc1[i] = f32x4{0,0,0,0}; }

    #pragma unroll
    for (int kb = 0; kb < 8; ++kb) {
        int kk = (kb & 3) * 32 + g * 8;
        bf16x8 a0 = *reinterpret_cast<const bf16x8*>(((kb < 4) ? pA0 : pB0) + kk);
        bf16x8 a1 = *reinterpret_cast<const bf16x8*>(((kb < 4) ? pA1 : pB1) + kk);
        int o = kb * 64 + g * 16;
        #pragma unroll
        for (int ct = 0; ct < 8; ++ct) {
            int c = ct * 16 + r16;
            bf16x8 b = *reinterpret_cast<const bf16x8*>(
                (const char*)wlds + ((size_t)c << 9) + (o ^ ((c & 7) << 4)));
            acc0[ct] = __builtin_amdgcn_mfma_f32_16x16x32_bf16(a0, b, acc0[ct], 0, 0, 0);
            acc1[ct] = __builtin_amdgcn_mfma_f32_16x16x32_bf16(a1, b, acc1[ct], 0, 0, 0);
        }
    }

    #pragma unroll
    for (int ct = 0; ct < 8; ++ct) {
        float bv = bias[ct * 16 + r16];
        #pragma unroll
        for (int r = 0; r < 4; ++r) {
            int orow0 = nodeBase + g * 4 + r;
            int orow1 = orow0 + 16;
            if (orow0 < nNodes) Y[(size_t)orow0 * 128 + ct * 16 + r16] = f2b1(acc0[ct][r] + bv);
            if (orow1 < nNodes) Y[(size_t)orow1 * 128 + ct * 16 + r16] = f2b1(acc1[ct][r] + bv);
        }
    }
}

// ---------------- MFMA GEMM layer 2 fused: [y_top | z2s] = h1 @ W2c, K=128 ----------------
// cols 0-63 -> out fp32 (+bias); cols 64-127 -> z2s bf16, pre-scaled by dinv[row]

__global__ __launch_bounds__(256) void gemm_mfma2(
    const ushort* __restrict__ H1, const ushort* __restrict__ W2ct,
    const float* __restrict__ bias, const float* __restrict__ dinv,
    float* __restrict__ Yout, ushort* __restrict__ Z2, int nNodes)
{
    __shared__ ushort wlds[128 * 128];   // 32 KB: [col][256B row], swizzled
    int t = threadIdx.x;

    #pragma unroll
    for (int it = 0; it < 8; ++it) {
        int i = it * 256 + t;           // 2048 chunks of 16B
        int c = i >> 4;                 // col 0..127
        int o = (i & 15) << 4;          // byte offset 0..240
        bf16x8 v = *reinterpret_cast<const bf16x8*>(W2ct + ((size_t)c << 7) + (o >> 1));
        *reinterpret_cast<bf16x8*>((char*)wlds + ((size_t)c << 8) + (o ^ ((c & 7) << 4))) = v;
    }
    __syncthreads();

    int wave = t >> 6, lane = t & 63;
    int r16 = lane & 15, g = lane >> 4;
    int nodeBase = blockIdx.x * 128 + wave * 32;

    int arow0 = nodeBase + r16;       if (arow0 > nNodes - 1) arow0 = nNodes - 1;
    int arow1 = nodeBase + 16 + r16;  if (arow1 > nNodes - 1) arow1 = nNodes - 1;
    const ushort* p0 = H1 + (size_t)arow0 * 128;
    const ushort* p1 = H1 + (size_t)arow1 * 128;

    f32x4 acc0[8], acc1[8];
    #pragma unroll
    for (int i = 0; i < 8; ++i) { acc0[i] = f32x4{0,0,0,0}; acc1[i] = f32x4{0,0,0,0}; }

    #pragma unroll
    for (int kb = 0; kb < 4; ++kb) {
        int kk = kb * 32 + g * 8;
        bf16x8 a0 = *reinterpret_cast<const bf16x8*>(p0 + kk);
        bf16x8 a1 = *reinterpret_cast<const bf16x8*>(p1 + kk);
        int o = kb * 64 + g * 16;
        #pragma unroll
        for (int ct = 0; ct < 8; ++ct) {
            int c = ct * 16 + r16;
            bf16x8 b = *reinterpret_cast<const bf16x8*>(
                (const char*)wlds + ((size_t)c << 8) + (o ^ ((c & 7) << 4)));
            acc0[ct] = __builtin_amdgcn_mfma_f32_16x16x32_bf16(a0, b, acc0[ct], 0, 0, 0);
            acc1[ct] = __builtin_amdgcn_mfma_f32_16x16x32_bf16(a1, b, acc1[ct], 0, 0, 0);
        }
    }

    // per-output-row dinv for the z2s halves
    float dv0[4], dv1[4];
    #pragma unroll
    for (int r = 0; r < 4; ++r) {
        int o0 = nodeBase + g * 4 + r;      if (o0 > nNodes - 1) o0 = nNodes - 1;
        int o1 = nodeBase + 16 + g * 4 + r; if (o1 > nNodes - 1) o1 = nNodes - 1;
        dv0[r] = dinv[o0]; dv1[r] = dinv[o1];
    }

    #pragma unroll
    for (int ct = 0; ct < 8; ++ct) {
        float bv = (ct < 4) ? bias[ct * 16 + r16] : 0.f;
        #pragma unroll
        for (int r = 0; r < 4; ++r) {
            int orow0 = nodeBase + g * 4 + r;
            int orow1 = orow0 + 16;
            if (ct < 4) {
                if (orow0 < nNodes) Yout[(size_t)orow0 * 64 + ct * 16 + r16] = acc0[ct][r] + bv;
                if (orow1 < nNodes) Yout[(size_t)orow1 * 64 + ct * 16 + r16] = acc1[ct][r] + bv;
            } else {
                if (orow0 < nNodes) Z2[(size_t)orow0 * 64 + (ct - 4) * 16 + r16] = f2b1(acc0[ct][r] * dv0[r]);
                if (orow1 < nNodes) Z2[(size_t)orow1 * 64 + (ct - 4) * 16 + r16] = f2b1(acc1[ct][r] * dv1[r]);
            }
        }
    }
}

// ---------------- host ----------------

extern "C" void kernel_launch(void* const* d_in, const int* in_sizes, int n_in,
                              void* d_out, int out_size, void* d_ws, size_t ws_size,
                              hipStream_t stream)
{
    const float* feats = (const float*)d_in[0];
    const int*   src   = (const int*)d_in[1];
    const int*   dst   = (const int*)d_in[2];
    const float* W1    = (const float*)d_in[3];
    const float* b1    = (const float*)d_in[4];
    const float* W2    = (const float*)d_in[5];
    const float* b2    = (const float*)d_in[6];
    float* out = (float*)d_out;

    const int N = in_sizes[0] / IN_DIM;
    const int E = in_sizes[1];
    const int NB = (N + 1023) / 1024;

    char* ws = (char*)d_ws;
    size_t off = 0;
    int*    deg    = (int*)(ws + off);    off = align256(off + (size_t)N * 4);
    int*    rowptr = (int*)(ws + off);    off = align256(off + (size_t)(N + 1) * 4);
    int*    pre    = (int*)(ws + off);    off = align256(off + (size_t)N * 4);
    int*    bsum   = (int*)(ws + off);    off = align256(off + (size_t)64 * 4);
    int*    rank   = (int*)(ws + off);    off = align256(off + (size_t)E * 4);
    void*   colv   = (void*)(ws + off);   off = align256(off + (size_t)E * 4);
    float*  dinv   = (float*)(ws + off);  off = align256(off + (size_t)N * 4);
    ushort* featb  = (ushort*)(ws + off); off = align256(off + (size_t)N * 128 * 2);
    ushort* featbs = (ushort*)(ws + off); off = align256(off + (size_t)(N + 1) * 128 * 2);
    ushort* x1b    = (ushort*)(ws + off); off = align256(off + (size_t)N * 128 * 2);
    ushort* h1b    = (ushort*)(ws + off); off = align256(off + (size_t)N * 128 * 2);
    ushort* z2s    = (ushort*)(ws + off); off = align256(off + (size_t)(N + 1) * 64 * 2);
    ushort* W1t    = (ushort*)(ws + off); off = align256(off + (size_t)256 * 128 * 2);
    ushort* W2ct   = (ushort*)(ws + off); off = align256(off + (size_t)128 * 128 * 2);

    // graph prep
    const int n16 = (N + 3) / 4;
    zero_kernel<<<(n16 + 255) / 256, 256, 0, stream>>>((int4*)deg, n16);
    hist_kernel<<<(E + 255) / 256, 256, 0, stream>>>(dst, deg, rank, E);
    scan_blocks<<<NB, 256, 0, stream>>>(deg, pre, bsum, N);
    scan_add<<<(N + 255) / 256, 256, 0, stream>>>(pre, bsum, deg, rowptr, dinv, N, E, NB);

    // phase2: CSR fill + conversions (both depend only on scan_add)
    const bool small = (N <= 65535);
    const int fillBlocks = ((E + 3) / 4 + 255) / 256;
    const int nbF = (N * 32 + 255) / 256;
    const int p2Blocks = fillBlocks + nbF + 128 + 64;
    if (small)
        phase2_kernel<ushort><<<p2Blocks, 256, 0, stream>>>(
            src, dst, rowptr, rank, (ushort*)colv, E, fillBlocks,
            feats, dinv, featb, featbs, z2s, N, nbF, W1, W1t, W2, W2ct);
    else
        phase2_kernel<uint><<<p2Blocks, 256, 0, stream>>>(
            src, dst, rowptr, rank, (uint*)colv, E, fillBlocks,
            feats, dinv, featb, featbs, z2s, N, nbF, W1, W1t, W2, W2ct);

    const int aggBlocks = (N * 64 + 255) / 256;
    const int gemmBlocks = (N + 127) / 128;

    // layer 1: x1 = -dinv * sum featbs[src] ; h1 = [x | x1] @ W1 + b1
    if (small)
        agg_sum128<ushort><<<aggBlocks, 256, 0, stream>>>(featbs, rowptr, (const ushort*)colv, dinv, x1b, N);
    else
        agg_sum128<uint><<<aggBlocks, 256, 0, stream>>>(featbs, rowptr, (const uint*)colv, dinv, x1b, N);
    gemm_mfma1<<<gemmBlocks, 256, 0, stream>>>(featb, x1b, W1t, b1, h1b, N);

    // layer 2: [y_top | z2s] = h1 @ W2c ; out = y_top - dinv * sum z2s[src]
    gemm_mfma2<<<gemmBlocks, 256, 0, stream>>>(h1b, W2ct, b2, dinv, out, z2s, N);
    if (small)
        agg_sum64<ushort><<<aggBlocks, 256, 0, stream>>>(z2s, rowptr, (const ushort*)colv, dinv, out, N);
    else
        agg_sum64<uint><<<aggBlocks, 256, 0, stream>>>(z2s, rowptr, (const uint*)colv, dinv, out, N);
}